// Round 5
// baseline (757.811 us; speedup 1.0000x reference)
//
#include <hip/hip_runtime.h>
#include <hip/hip_bf16.h>
#include <math.h>

#define S_LEN  2048
#define MDIM   4096
#define NHEADS 32
#define NKV    8
#define HD     128
#define KVDIM  1024
#define NFUSED (MDIM + 2 * KVDIM) /* 6144 */

typedef short bf16x8 __attribute__((ext_vector_type(8)));
typedef float f32x4 __attribute__((ext_vector_type(4)));

__device__ __forceinline__ unsigned short f2b(float f) {
  union { float f; unsigned int u; } v; v.f = f;
  unsigned int r = v.u + 0x7FFFu + ((v.u >> 16) & 1u);
  return (unsigned short)(r >> 16);
}
__device__ __forceinline__ float b2f(unsigned short h) {
  union { unsigned int u; float f; } v; v.u = ((unsigned int)h) << 16;
  return v.f;
}

// async global->LDS, 16B per lane; lds dest = wave-uniform base + lane*16
__device__ __forceinline__ void async_copy16(const void* g, void* l) {
  __builtin_amdgcn_global_load_lds(
      (const __attribute__((address_space(1))) unsigned int*)g,
      (__attribute__((address_space(3))) unsigned int*)l, 16, 0, 0);
}

// ---------------------------------------------------------------------------
// x f32 -> bf16 (one thread per 8 elements)
// ---------------------------------------------------------------------------
__global__ __launch_bounds__(256) void convert_x(
    const float* __restrict__ src, unsigned short* __restrict__ dst) {
  size_t i = (size_t)blockIdx.x * 256 + threadIdx.x;
  const float4 a = ((const float4*)src)[2 * i];
  const float4 b = ((const float4*)src)[2 * i + 1];
  unsigned short o[8] = {f2b(a.x), f2b(a.y), f2b(a.z), f2b(a.w),
                         f2b(b.x), f2b(b.y), f2b(b.z), f2b(b.w)};
  *(int4*)(dst + 8 * i) = *(const int4*)o;
}

// ---------------------------------------------------------------------------
// RoPE table: rtab[s*64+d] = (cos, sin)(s * 50000^(-d/64)). One-time, ~4us.
// Removes ~13us of serial cosf/sinf VALU from gemm1's 1-block/CU epilogue.
// ---------------------------------------------------------------------------
__global__ __launch_bounds__(256) void rope_table(float2* __restrict__ rtab) {
  int t = blockIdx.x * 256 + threadIdx.x;  // 0..131071
  int s = t >> 6, d = t & 63;
  float inv_freq = __expf(-0.16905903569f * (float)d);  // 50000^(-d/64)
  float ang = (float)s * inv_freq;
  rtab[t] = make_float2(cosf(ang), sinf(ang));
}

// ---------------------------------------------------------------------------
// Transpose + convert: W [K][N] f32 -> WT [N][K] bf16. 64x64 tiles.
// ---------------------------------------------------------------------------
__global__ __launch_bounds__(256) void transpose_convert(
    const float* __restrict__ W, unsigned short* __restrict__ WT, int K,
    int N) {
  __shared__ unsigned short t[64 * 72];  // [n][k], pad 64->72
  const int k0 = blockIdx.y << 6, n0 = blockIdx.x << 6;
  const int tid = threadIdx.x;
#pragma unroll
  for (int it = 0; it < 4; ++it) {
    int idx = it * 256 + tid;          // 0..1023
    int r = idx & 63;                  // k row
    int c = ((idx >> 6) & 15) << 2;    // n col group
    const float4 v = *(const float4*)(W + (size_t)(k0 + r) * N + n0 + c);
    t[(c + 0) * 72 + r] = f2b(v.x);
    t[(c + 1) * 72 + r] = f2b(v.y);
    t[(c + 2) * 72 + r] = f2b(v.z);
    t[(c + 3) * 72 + r] = f2b(v.w);
  }
  __syncthreads();
  const int n = tid >> 2, kk = (tid & 3) << 4;
  *(int4*)(WT + (size_t)(n0 + n) * K + k0 + kk) = *(int4*)&t[n * 72 + kk];
  *(int4*)(WT + (size_t)(n0 + n) * K + k0 + kk + 8) =
      *(int4*)&t[n * 72 + kk + 8];
}

// ---------------------------------------------------------------------------
// GEMM1: fused = xb[2048][4096](bf16) * WT^T + bqkv, RoPE + head-split.
// 256x256 tile, BK=64, **4 waves** (2M x 2N, 128x128 per wave), dbuf 128KiB.
//
// Why 4 waves + intra-wave pipeline: at 8 waves the LDS-read pipe
// (192 KB/K-tile, ~2800cyc) exceeded the MFMA pipe (2480cyc) and the
// barrier-phased schedule serialized them (observed 5280cyc/K-tile, 137us,
// MfmaUtil 31% across 3 schedule variants). With 2x2 waves each element is
// read only 2x: 128 KB/K-tile (~2050cyc) < MFMA (2480cyc) -> MFMA-bound by
// construction. Overlap is intra-wave software pipelining with counted
// lgkmcnt: issue next chunk's 4-12 ds_read_b128, wait lgkmcnt(4/12) (= only
// the previous chunk's reads, DS completes in order), MFMA 32 on ready regs
// while new reads drain. sched_barrier(0) after every wait (rule #18).
// One vmcnt(0)+s_barrier per K-tile (copies have >=1300cyc flight - free).
// Regs: acc 8x8 f32x4 = 256 AGPR + ~130 frag/addr VGPR at 1 wave/SIMD
// (launch_bounds(256,1) -> 512-reg budget, no spill below ~450 per m08).
// Bank conflicts: per-row XOR chunk swizzle on pre-swizzled global source
// (LDS dest linear for global_load_lds) + same XOR on ds_read chunk.
// ---------------------------------------------------------------------------
__global__ __launch_bounds__(256, 1) void gemm1_kernel(
    const unsigned short* __restrict__ xb,
    const unsigned short* __restrict__ WT, const float* __restrict__ bias,
    const float2* __restrict__ rtab, unsigned short* __restrict__ Qb,
    unsigned short* __restrict__ Kb, unsigned short* __restrict__ Vt) {
  // [slot][ A 256x64 | B 256x64 ] bf16 = 2 x 64KiB = 128KiB
  __shared__ unsigned short sm[2][32768];

  const int tid = threadIdx.x;
  const int bn = blockIdx.x, bm = blockIdx.y;
  const int lane = tid & 63, wave = tid >> 6;  // 4 waves
  const int lrow = lane & 15, quad = lane >> 4;
  const int wrow = wave >> 1, wcol = wave & 1;  // 2M x 2N wave grid

  f32x4 acc[8][8];
#pragma unroll
  for (int i = 0; i < 8; ++i)
#pragma unroll
    for (int j = 0; j < 8; ++j) {
      f32x4 z = {0.f, 0.f, 0.f, 0.f};
      acc[i][j] = z;
    }

  // staging: wave w owns rows [w*64, w*64+64) of each panel = 8 copies of
  // 8 rows. lane -> (row lane>>3, chunk lane&7); r&7 == lane>>3.
  const size_t swz = (size_t)(((lane & 7) ^ (lane >> 3)) << 3);
  const unsigned short* sA =
      xb + (size_t)(bm * 256 + wave * 64 + (lane >> 3)) * MDIM + swz;
  const unsigned short* sB =
      WT + (size_t)(bn * 256 + wave * 64 + (lane >> 3)) * MDIM + swz;

  auto stageA4 = [&](int slot, int k0, int m0) {
#pragma unroll
    for (int m = m0; m < m0 + 4; ++m)
      async_copy16(sA + (size_t)m * 8 * MDIM + k0,
                   &sm[slot][(wave * 64 + m * 8) * 64]);
  };
  auto stageB4 = [&](int slot, int k0, int m0) {
#pragma unroll
    for (int m = m0; m < m0 + 4; ++m)
      async_copy16(sB + (size_t)m * 8 * MDIM + k0,
                   &sm[slot][16384 + (wave * 64 + m * 8) * 64]);
  };

  // fragment-read invariants (row&7 == lrow&7 for all frags)
  const int arow = wrow * 128 + lrow;
  const int brow = wcol * 128 + lrow;
  const int co0 = (quad ^ (lrow & 7)) << 3;
  const int co1 = ((4 + quad) ^ (lrow & 7)) << 3;

  // prologue: K-tile 0 -> slot 0 (16 copies/wave)
  stageA4(0, 0, 0);
  stageA4(0, 0, 4);
  stageB4(0, 0, 0);
  stageB4(0, 0, 4);

#pragma unroll 1
  for (int kt = 0; kt < 64; ++kt) {
    const int p = kt & 1;
    // slot-p copies (issued last tile, >=1300cyc flight) land; slot p^1 free
    asm volatile("s_waitcnt vmcnt(0)" ::: "memory");
    __builtin_amdgcn_s_barrier();
    __builtin_amdgcn_sched_barrier(0);

    const unsigned short* Asl = &sm[p][0];
    const unsigned short* Bsl = &sm[p][16384];
    const int kn0 = (kt + 1) << 6;
    const bool pref = kt < 63;
    bf16x8 b0[8], b1[8], a0[4], a1[4], a2[4], a3[4];

    // R0: 8B + 4A @ kk0
#pragma unroll
    for (int j = 0; j < 8; ++j)
      b0[j] = *(const bf16x8*)&Bsl[(brow + j * 16) * 64 + co0];
#pragma unroll
    for (int i = 0; i < 4; ++i)
      a0[i] = *(const bf16x8*)&Asl[(arow + i * 16) * 64 + co0];
    if (pref) {
      stageA4(p ^ 1, kn0, 0);
      stageA4(p ^ 1, kn0, 4);
    }
    // R1: 4A rows 64..127 @ kk0
#pragma unroll
    for (int i = 0; i < 4; ++i)
      a1[i] = *(const bf16x8*)&Asl[(arow + (4 + i) * 16) * 64 + co0];
    asm volatile("s_waitcnt lgkmcnt(4)" ::: "memory");  // R0 done, R1 flies
    __builtin_amdgcn_sched_barrier(0);
    __builtin_amdgcn_s_setprio(1);
#pragma unroll
    for (int i = 0; i < 4; ++i)
#pragma unroll
      for (int j = 0; j < 8; ++j)
        acc[i][j] = __builtin_amdgcn_mfma_f32_16x16x32_bf16(a0[i], b0[j],
                                                            acc[i][j], 0, 0, 0);
    __builtin_amdgcn_s_setprio(0);
    if (pref) stageB4(p ^ 1, kn0, 0);
    // R2: 8B + 4A @ kk1
#pragma unroll
    for (int j = 0; j < 8; ++j)
      b1[j] = *(const bf16x8*)&Bsl[(brow + j * 16) * 64 + co1];
#pragma unroll
    for (int i = 0; i < 4; ++i)
      a2[i] = *(const bf16x8*)&Asl[(arow + i * 16) * 64 + co1];
    asm volatile("s_waitcnt lgkmcnt(12)" ::: "memory");  // R1 done, R2 flies
    __builtin_amdgcn_sched_barrier(0);
    __builtin_amdgcn_s_setprio(1);
#pragma unroll
    for (int i = 0; i < 4; ++i)
#pragma unroll
      for (int j = 0; j < 8; ++j)
        acc[4 + i][j] = __builtin_amdgcn_mfma_f32_16x16x32_bf16(
            a1[i], b0[j], acc[4 + i][j], 0, 0, 0);
    __builtin_amdgcn_s_setprio(0);
    if (pref) stageB4(p ^ 1, kn0, 4);
    // R3: 4A rows 64..127 @ kk1
#pragma unroll
    for (int i = 0; i < 4; ++i)
      a3[i] = *(const bf16x8*)&Asl[(arow + (4 + i) * 16) * 64 + co1];
    asm volatile("s_waitcnt lgkmcnt(4)" ::: "memory");  // R2 done, R3 flies
    __builtin_amdgcn_sched_barrier(0);
    __builtin_amdgcn_s_setprio(1);
#pragma unroll
    for (int i = 0; i < 4; ++i)
#pragma unroll
      for (int j = 0; j < 8; ++j)
        acc[i][j] = __builtin_amdgcn_mfma_f32_16x16x32_bf16(a2[i], b1[j],
                                                            acc[i][j], 0, 0, 0);
    __builtin_amdgcn_s_setprio(0);
    asm volatile("s_waitcnt lgkmcnt(0)" ::: "memory");  // R3 done
    __builtin_amdgcn_sched_barrier(0);
    __builtin_amdgcn_s_setprio(1);
#pragma unroll
    for (int i = 0; i < 4; ++i)
#pragma unroll
      for (int j = 0; j < 8; ++j)
        acc[4 + i][j] = __builtin_amdgcn_mfma_f32_16x16x32_bf16(
            a3[i], b1[j], acc[4 + i][j], 0, 0, 0);
    __builtin_amdgcn_s_setprio(0);
  }
  __syncthreads();  // K-loop reads done before Ct overwrites staging LDS

  // ---- epilogue: two 128-col halves; Ct[256][132] reuses staging LDS ----
  unsigned short* Ct = &sm[0][0];
#pragma unroll 1
  for (int h = 0; h < 2; ++h) {
    const int slot = 2 * bn + h;  // 0..31 Q, 32..39 K, 40..47 V
    if (wcol == h) {              // 2 waves (wrow 0,1) own this col half
#pragma unroll
      for (int i = 0; i < 8; ++i)
#pragma unroll
        for (int j = 0; j < 8; ++j) {
          int lc = j * 16 + lrow;
          float bv = bias[slot * 128 + lc];
#pragma unroll
          for (int r = 0; r < 4; ++r) {
            int lrw = wrow * 128 + i * 16 + quad * 4 + r;
            Ct[lrw * 132 + lc] = f2b(acc[i][j][r] + bv);
          }
        }
    }
    __syncthreads();

    if (slot < 40) {
#pragma unroll 4
      for (int it = 0; it < 64; ++it) {
        int row = it * 4 + wave;  // 0..255
        int d = lane;
        float x1 = b2f(Ct[row * 132 + d]);
        float x2 = b2f(Ct[row * 132 + d + 64]);
        int s = bm * 256 + row;
        float2 cs = rtab[s * 64 + d];  // (cos, sin) precomputed
        float o1 = x1 * cs.x - x2 * cs.y;
        float o2 = x2 * cs.x + x1 * cs.y;
        unsigned short* dst;
        if (slot < 32)
          dst = Qb + ((size_t)slot * S_LEN + s) * HD;
        else
          dst = Kb + ((size_t)(slot - 32) * S_LEN + s) * HD;
        dst[d] = f2b(o1);
        dst[d + 64] = f2b(o2);
      }
    } else {
      // V: write transposed Vt[g][d][s], coalesced along s
      const int g = slot - 40;
      unsigned short* Vtg = Vt + (size_t)g * HD * S_LEN;  // [128][2048]
      const int dp = tid >> 2;         // d-pair 0..63
      const int sq = (tid & 3) << 5;   // s-quarter 0,32,64,96
#pragma unroll 1
      for (int vc = 0; vc < 2; ++vc) {
        unsigned short buf0[32], buf1[32];
#pragma unroll
        for (int i = 0; i < 32; ++i) {
          unsigned int w =
              *(const unsigned int*)&Ct[(vc * 128 + sq + i) * 132 + 2 * dp];
          buf0[i] = (unsigned short)(w & 0xffffu);
          buf1[i] = (unsigned short)(w >> 16);
        }
        const int s0 = bm * 256 + vc * 128 + sq;
#pragma unroll
        for (int c = 0; c < 2; ++c) {
          unsigned short* dst = Vtg + (size_t)(2 * dp + c) * S_LEN + s0;
          const unsigned short* b = c ? buf1 : buf0;
#pragma unroll
          for (int q4 = 0; q4 < 4; ++q4)
            *(int4*)(dst + q4 * 8) = *(const int4*)(b + q4 * 8);
        }
      }
    }
    __syncthreads();  // pass-h reads done before pass h+1 overwrites Ct
  }
}

// ---------------------------------------------------------------------------
// GEMM2: out = attnb[2048][4096](bf16) * WoT^T + bo (f32 out).
// BM=128 x BN=256 (grid 16x16 = 256 blocks = 1/CU), BK=64, 8 waves (2M x 4N,
// 64x64 per wave), dbuf 96KiB LDS, 2-phase-per-K-tile schedule.
// ---------------------------------------------------------------------------
__global__ __launch_bounds__(512, 2) void gemm2_kernel(
    const unsigned short* __restrict__ Ab16,
    const unsigned short* __restrict__ BT, const float* __restrict__ bias,
    float* __restrict__ C) {
  // [slot][ A 128x64 | B 256x64 ] bf16 = 2 x 48KiB = 96KiB
  __shared__ unsigned short sm[2][24576];

  const int tid = threadIdx.x;
  const int bn = blockIdx.x, bm = blockIdx.y;  // bn: N/256, bm: M/128
  const int lane = tid & 63, wave = tid >> 6;
  const int lrow = lane & 15, quad = lane >> 4;
  const int wrow = wave >> 2, wcol = wave & 3;  // 2M x 4N wave grid

  f32x4 acc[4][4];
#pragma unroll
  for (int i = 0; i < 4; ++i)
#pragma unroll
    for (int j = 0; j < 4; ++j) {
      f32x4 z = {0.f, 0.f, 0.f, 0.f};
      acc[i][j] = z;
    }

  const int lr8 = lane >> 3, lc8 = lane & 7;
  const int baser = wave * 8 + lr8;
  const size_t swz = (size_t)((lc8 ^ (baser & 7)) << 3);
  const unsigned short* sA = Ab16 + (size_t)(bm * 128 + baser) * MDIM + swz;
  const unsigned short* sB = BT + (size_t)(bn * 256 + baser) * MDIM + swz;

  auto stageA2 = [&](int slot, int k0) {
#pragma unroll
    for (int c = 0; c < 2; ++c)
      async_copy16(sA + (size_t)c * 64 * MDIM + k0,
                   &sm[slot][(c * 64 + wave * 8) * 64]);
  };
  auto stageB1 = [&](int slot, int k0, int c) {
    async_copy16(sB + (size_t)c * 64 * MDIM + k0,
                 &sm[slot][8192 + (c * 64 + wave * 8) * 64]);
  };

  const int arow = wrow * 64 + lrow;
  const int brow = wcol * 64 + lrow;
  const int co0 = (quad ^ (lrow & 7)) << 3;
  const int co1 = ((4 + quad) ^ (lrow & 7)) << 3;

  // prologue: K-tile 0 -> slot 0
  stageA2(0, 0);
  stageB1(0, 0, 0);
  stageB1(0, 0, 1);
  stageB1(0, 0, 2);
  stageB1(0, 0, 3);

#pragma unroll 1
  for (int kt = 0; kt < 64; ++kt) {
    const int p = kt & 1;
    asm volatile("s_waitcnt vmcnt(0)" ::: "memory");
    __builtin_amdgcn_s_barrier();
    __builtin_amdgcn_sched_barrier(0);

    const unsigned short* Asl = &sm[p][0];
    const unsigned short* Bsl = &sm[p][8192];
    const int kn0 = (kt + 1) << 6;
    const bool pref = kt < 63;
    bf16x8 bfr[4], af[4];

    // ---- P0: kk=0 (reads 4B+4A, stage A c0..1 + B c0) ----
#pragma unroll
    for (int j = 0; j < 4; ++j)
      bfr[j] = *(const bf16x8*)&Bsl[(brow + j * 16) * 64 + co0];
#pragma unroll
    for (int i = 0; i < 4; ++i)
      af[i] = *(const bf16x8*)&Asl[(arow + i * 16) * 64 + co0];
    if (pref) {
      stageA2(p ^ 1, kn0);
      stageB1(p ^ 1, kn0, 0);
    }
    __builtin_amdgcn_s_barrier();
    asm volatile("s_waitcnt lgkmcnt(0)" ::: "memory");
    __builtin_amdgcn_sched_barrier(0);
    __builtin_amdgcn_s_setprio(1);
#pragma unroll
    for (int i = 0; i < 4; ++i)
#pragma unroll
      for (int j = 0; j < 4; ++j)
        acc[i][j] = __builtin_amdgcn_mfma_f32_16x16x32_bf16(af[i], bfr[j],
                                                            acc[i][j], 0, 0, 0);
    __builtin_amdgcn_s_setprio(0);
    __builtin_amdgcn_s_barrier();

    // ---- P1: kk=1 (reads 4B+4A, stage B c1..3; no trailing bar) ----
#pragma unroll
    for (int j = 0; j < 4; ++j)
      bfr[j] = *(const bf16x8*)&Bsl[(brow + j * 16) * 64 + co1];
#pragma unroll
    for (int i = 0; i < 4; ++i)
      af[i] = *(const bf16x8*)&Asl[(arow + i * 16) * 64 + co1];
    if (pref) {
      stageB1(p ^ 1, kn0, 1);
      stageB1(p ^ 1, kn0, 2);
      stageB1(p ^ 1, kn0, 3);
    }
    __builtin_amdgcn_s_barrier();
    asm volatile("s_waitcnt lgkmcnt(0)" ::: "memory");
    __builtin_amdgcn_sched_barrier(0);
    __builtin_amdgcn_s_setprio(1);
#pragma unroll
    for (int i = 0; i < 4; ++i)
#pragma unroll
      for (int j = 0; j < 4; ++j)
        acc[i][j] = __builtin_amdgcn_mfma_f32_16x16x32_bf16(af[i], bfr[j],
                                                            acc[i][j], 0, 0, 0);
    __builtin_amdgcn_s_setprio(0);
  }

  // epilogue: direct f32 store with bias
#pragma unroll
  for (int i = 0; i < 4; ++i)
#pragma unroll
    for (int j = 0; j < 4; ++j) {
      int gcol = bn * 256 + wcol * 64 + j * 16 + lrow;
      float bv = bias[gcol];
#pragma unroll
      for (int r = 0; r < 4; ++r) {
        int grow = bm * 128 + wrow * 64 + i * 16 + quad * 4 + r;
        C[(size_t)grow * MDIM + gcol] = acc[i][j][r] + bv;
      }
    }
}

// ---------------------------------------------------------------------------
// Flash attention, causal, GQA. Fixed-max softmax (scores bounded; exp(s-12)
// cannot overflow, o/l unchanged). Q in registers. K/V double-buffered LDS
// via global_load_lds with XOR-swizzled layout (pre-swizzled global source,
// linear LDS dest). One vmcnt(0)+barrier per KV-tile; prefetch issued after
// the barrier flies under the whole compute phase. Ps fence: lgkmcnt only.
// Row-sums via ones-MFMA. 1D LPT grid.
// ---------------------------------------------------------------------------
__device__ __forceinline__ void stage_kv(const unsigned short* __restrict__ Kg,
                                         const unsigned short* __restrict__ Vg,
                                         int jtile, unsigned short* KsBuf,
                                         unsigned short* VsBuf, int wv,
                                         int lane) {
  const unsigned short* kg = Kg + (size_t)jtile * 64 * HD;
  const unsigned short* vg = Vg + jtile * 64;
#pragma unroll
  for (int it = 0; it < 4; ++it) {
    // K: 4 rows x 256B per copy; lane -> row base+(l>>4), chunk l&15
    int kr = wv * 16 + it * 4 + (lane >> 4);
    async_copy16(kg + (size_t)kr * HD + (((lane & 15) ^ (kr & 7)) << 3),
                 KsBuf + (wv * 16 + it * 4) * 128);
    // V: 8 rows x 128B per copy; lane -> row base+(l>>3), chunk l&7
    int vr = wv * 32 + it * 8 + (lane >> 3);
    async_copy16(vg + (size_t)vr * S_LEN + (((lane & 7) ^ (vr & 7)) << 3),
                 VsBuf + (wv * 32 + it * 8) * 64);
  }
}

__global__ __launch_bounds__(256, 2) void flash_kernel(
    const unsigned short* __restrict__ Qb, const unsigned short* __restrict__ Kb,
    const unsigned short* __restrict__ Vt, unsigned short* __restrict__ attnb) {
  __shared__ __align__(16) unsigned short Ks[2][64 * 128];  // [krow][d] swz
  __shared__ __align__(16) unsigned short Vs[2][128 * 64];  // [d][kvpos] swz
  __shared__ __align__(16) unsigned short Ps[64 * 72];      // [qrow][kvpos]

  const int tid = threadIdx.x;
  const int bid = blockIdx.x;
  const int h = bid & 31;
  const int qt = 31 - (bid >> 5);  // heavy tiles dispatch first (LPT)
  const int g = h >> 2;
  const int wv = tid >> 6, lane = tid & 63;
  const int lrow = lane & 15, quad = lane >> 4;
  const float scale = 0.08838834764831845f;  // 1/sqrt(128)

  const unsigned short* Qg = Qb + ((size_t)h * S_LEN + qt * 64) * HD;
  bf16x8 qf[4];
#pragma unroll
  for (int ks = 0; ks < 4; ++ks)
    qf[ks] = *(const bf16x8*)(Qg + (size_t)(wv * 16 + lrow) * HD + ks * 32 +
                              quad * 8);

  // all-ones bf16 B-fragment for row-sum MFMA
  bf16x8 ones;
#pragma unroll
  for (int i = 0; i < 8; ++i) ones[i] = (short)0x3F80;

  const unsigned short* Kg = Kb + (size_t)g * S_LEN * HD;   // [s][d]
  const unsigned short* Vg = Vt + (size_t)g * HD * S_LEN;   // [d][s]

  f32x4 l_acc = {0.f, 0.f, 0.f, 0.f};
  f32x4 o_acc[8];
#pragma unroll
  for (int jc = 0; jc < 8; ++jc) {
    f32x4 z = {0.f, 0.f, 0.f, 0.f};
    o_acc[jc] = z;
  }

  // prologue: stage tile 0 into buffer 0
  stage_kv(Kg, Vg, 0, &Ks[0][0], &Vs[0][0], wv, lane);

  for (int jt = 0; jt <= qt; ++jt) {
    const int cb = jt & 1;
    // own copies of tile jt are the only outstanding VMEM ops
    asm volatile("s_waitcnt vmcnt(0)" ::: "memory");
    __builtin_amdgcn_s_barrier();  // all waves' copies landed; all waves
                                   // done reading buf cb from iter jt-2
    __builtin_amdgcn_sched_barrier(0);

    if (jt < qt)  // prefetch next tile; flies under this iter's compute
      stage_kv(Kg, Vg, jt + 1, &Ks[cb ^ 1][0], &Vs[cb ^ 1][0], wv, lane);

    // S = Q K^T (wave's 16 rows x 64 cols)
    f32x4 s_acc[4];
#pragma unroll
    for (int j = 0; j < 4; ++j) {
      f32x4 z = {0.f, 0.f, 0.f, 0.f};
      s_acc[j] = z;
    }
#pragma unroll
    for (int ks = 0; ks < 4; ++ks)
#pragma unroll
      for (int j = 0; j < 4; ++j) {
        int row = j * 16 + lrow;
        bf16x8 bk = *(const bf16x8*)&Ks[cb][row * 128 +
                                           (((ks * 4 + quad) ^ (row & 7)) << 3)];
        s_acc[j] = __builtin_amdgcn_mfma_f32_16x16x32_bf16(qf[ks], bk,
                                                           s_acc[j], 0, 0, 0);
      }

    // fixed-max softmax: p = exp(s*scale - 12); mask only on diagonal tile
    if (jt == qt) {
#pragma unroll
      for (int r = 0; r < 4; ++r) {
        int grow = qt * 64 + wv * 16 + quad * 4 + r;
#pragma unroll
        for (int j = 0; j < 4; ++j) {
          int gcol = jt * 64 + j * 16 + lrow;
          float p =
              (gcol <= grow) ? __expf(s_acc[j][r] * scale - 12.0f) : 0.f;
          Ps[(wv * 16 + quad * 4 + r) * 72 + j * 16 + lrow] = f2b(p);
        }
      }
    } else {
#pragma unroll
      for (int r = 0; r < 4; ++r)
#pragma unroll
        for (int j = 0; j < 4; ++j) {
          float p = __expf(s_acc[j][r] * scale - 12.0f);
          Ps[(wv * 16 + quad * 4 + r) * 72 + j * 16 + lrow] = f2b(p);
        }
    }
    // Ps band is wave-private: LDS drain only (must NOT drain vmcnt — the
    // next tile's global_load_lds copies are in flight)
    asm volatile("s_waitcnt lgkmcnt(0)" ::: "memory");
    __builtin_amdgcn_sched_barrier(0);

    // O += P V (16 rows x 128 cols, K=64); l += P * ones
#pragma unroll
    for (int kk = 0; kk < 2; ++kk) {
      bf16x8 ap =
          *(const bf16x8*)&Ps[(wv * 16 + lrow) * 72 + kk * 32 + 8 * quad];
      l_acc = __builtin_amdgcn_mfma_f32_16x16x32_bf16(ap, ones, l_acc, 0, 0, 0);
#pragma unroll
      for (int jc = 0; jc < 8; ++jc) {
        int row = jc * 16 + lrow;
        bf16x8 bv = *(const bf16x8*)&Vs[cb][row * 64 +
                                            (((kk * 4 + quad) ^ (row & 7)) << 3)];
        o_acc[jc] = __builtin_amdgcn_mfma_f32_16x16x32_bf16(ap, bv, o_acc[jc],
                                                            0, 0, 0);
      }
    }
    __builtin_amdgcn_s_barrier();  // all waves done reading buf cb before
                                   // iter jt+1 issues copies into buf cb
  }

  // epilogue: O / l -> attnb[s][h*128+d] (bf16)
#pragma unroll
  for (int r = 0; r < 4; ++r) {
    float inv_l = 1.0f / l_acc[r];
    int row = qt * 64 + wv * 16 + quad * 4 + r;
#pragma unroll
    for (int jc = 0; jc < 8; ++jc) {
      int col = jc * 16 + lrow;
      attnb[(size_t)row * MDIM + h * HD + col] = f2b(o_acc[jc][r] * inv_l);
    }
  }
}

// ---------------------------------------------------------------------------
extern "C" void kernel_launch(void* const* d_in, const int* in_sizes, int n_in,
                              void* d_out, int out_size, void* d_ws,
                              size_t ws_size, hipStream_t stream) {
  const float* x = (const float*)d_in[0];
  const float* Wqkv = (const float*)d_in[1];
  const float* bqkv = (const float*)d_in[2];
  const float* Wo = (const float*)d_in[3];
  const float* bo = (const float*)d_in[4];
  float* out = (float*)d_out;

  unsigned char* ws = (unsigned char*)d_ws;
  // region A [0, 50331648): phase1 = WT (6144x4096 bf16);
  //                         phase2 = WoT (33554432) + attnb (16777216)
  unsigned short* WT = (unsigned short*)ws;
  unsigned short* WoT = (unsigned short*)ws;
  unsigned short* attnb = (unsigned short*)(ws + 33554432);
  // region B: Q/K head-major bf16, V transposed [g][d][s]
  unsigned short* Qb = (unsigned short*)(ws + 50331648);  // 32*2048*128
  unsigned short* Kb = (unsigned short*)(ws + 67108864);  // 8*2048*128
  unsigned short* Vt = (unsigned short*)(ws + 71303168);  // 8*128*2048
  // d_out scratch: xb (bf16 x) in [0,16MB); RoPE table in [16MB,17MB).
  // Both consumed before gemm2 overwrites d_out with the final output.
  unsigned short* xb = (unsigned short*)d_out;
  float2* rtab = (float2*)((unsigned char*)d_out + 16777216);

  // 0. x f32 -> bf16 (into d_out scratch) + RoPE cos/sin table
  convert_x<<<(S_LEN * MDIM / 8) / 256, 256, 0, stream>>>(x, xb);
  rope_table<<<(S_LEN * 64) / 256, 256, 0, stream>>>(rtab);
  // 1. Wqkv [4096][6144] f32 -> WT [6144][4096] bf16
  transpose_convert<<<dim3(NFUSED / 64, MDIM / 64), 256, 0, stream>>>(
      Wqkv, WT, MDIM, NFUSED);
  // 2. QKV GEMM with fused bias + RoPE + head split (V transposed)
  gemm1_kernel<<<dim3(NFUSED / 256, S_LEN / 256), 256, 0, stream>>>(
      xb, WT, bqkv, rtab, Qb, Kb, Vt);
  // 3. Wo [4096][4096] f32 -> WoT [4096][4096] bf16 (reuses WT region)
  transpose_convert<<<dim3(MDIM / 64, MDIM / 64), 256, 0, stream>>>(Wo, WoT,
                                                                    MDIM, MDIM);
  // 4. causal GQA flash attention -> attnb bf16 (1D LPT grid)
  flash_kernel<<<S_LEN / 64 * NHEADS, 256, 0, stream>>>(Qb, Kb, Vt, attnb);
  // 5. output projection (overwrites xb scratch region of d_out)
  gemm2_kernel<<<dim3(MDIM / 256, S_LEN / 128), 512, 0, stream>>>(attnb, WoT,
                                                                  bo, out);
}

// Round 6
// 487.577 us; speedup vs baseline: 1.5542x; 1.5542x over previous
//
#include <hip/hip_runtime.h>
#include <hip/hip_bf16.h>
#include <math.h>

#define S_LEN  2048
#define MDIM   4096
#define NHEADS 32
#define NKV    8
#define HD     128
#define KVDIM  1024
#define NFUSED (MDIM + 2 * KVDIM) /* 6144 */

typedef short bf16x8 __attribute__((ext_vector_type(8)));
typedef float f32x4 __attribute__((ext_vector_type(4)));

__device__ __forceinline__ unsigned short f2b(float f) {
  union { float f; unsigned int u; } v; v.f = f;
  unsigned int r = v.u + 0x7FFFu + ((v.u >> 16) & 1u);
  return (unsigned short)(r >> 16);
}
__device__ __forceinline__ float b2f(unsigned short h) {
  union { unsigned int u; float f; } v; v.u = ((unsigned int)h) << 16;
  return v.f;
}

// async global->LDS, 16B per lane; lds dest = wave-uniform base + lane*16
__device__ __forceinline__ void async_copy16(const void* g, void* l) {
  __builtin_amdgcn_global_load_lds(
      (const __attribute__((address_space(1))) unsigned int*)g,
      (__attribute__((address_space(3))) unsigned int*)l, 16, 0, 0);
}

// ---------------------------------------------------------------------------
// x f32 -> bf16 (one thread per 8 elements)
// ---------------------------------------------------------------------------
__global__ __launch_bounds__(256) void convert_x(
    const float* __restrict__ src, unsigned short* __restrict__ dst) {
  size_t i = (size_t)blockIdx.x * 256 + threadIdx.x;
  const float4 a = ((const float4*)src)[2 * i];
  const float4 b = ((const float4*)src)[2 * i + 1];
  unsigned short o[8] = {f2b(a.x), f2b(a.y), f2b(a.z), f2b(a.w),
                         f2b(b.x), f2b(b.y), f2b(b.z), f2b(b.w)};
  *(int4*)(dst + 8 * i) = *(const int4*)o;
}

// ---------------------------------------------------------------------------
// RoPE table: rtab[s*64+d] = (cos, sin)(s * 50000^(-d/64)). One-time, ~4us.
// Removes ~60-cyc transcendental chains/element from gemm1's serial epilogue
// (1 block/CU; VALUBusy was 20% with on-the-fly cosf/sinf).
// ---------------------------------------------------------------------------
__global__ __launch_bounds__(256) void rope_table(float2* __restrict__ rtab) {
  int t = blockIdx.x * 256 + threadIdx.x;  // 0..131071
  int s = t >> 6, d = t & 63;
  float inv_freq = __expf(-0.16905903569f * (float)d);  // 50000^(-d/64)
  float ang = (float)s * inv_freq;
  rtab[t] = make_float2(cosf(ang), sinf(ang));
}

// ---------------------------------------------------------------------------
// Transpose + convert: W [K][N] f32 -> WT [N][K] bf16. 64x64 tiles.
// ---------------------------------------------------------------------------
__global__ __launch_bounds__(256) void transpose_convert(
    const float* __restrict__ W, unsigned short* __restrict__ WT, int K,
    int N) {
  __shared__ unsigned short t[64 * 72];  // [n][k], pad 64->72
  const int k0 = blockIdx.y << 6, n0 = blockIdx.x << 6;
  const int tid = threadIdx.x;
#pragma unroll
  for (int it = 0; it < 4; ++it) {
    int idx = it * 256 + tid;          // 0..1023
    int r = idx & 63;                  // k row
    int c = ((idx >> 6) & 15) << 2;    // n col group
    const float4 v = *(const float4*)(W + (size_t)(k0 + r) * N + n0 + c);
    t[(c + 0) * 72 + r] = f2b(v.x);
    t[(c + 1) * 72 + r] = f2b(v.y);
    t[(c + 2) * 72 + r] = f2b(v.z);
    t[(c + 3) * 72 + r] = f2b(v.w);
  }
  __syncthreads();
  const int n = tid >> 2, kk = (tid & 3) << 4;
  *(int4*)(WT + (size_t)(n0 + n) * K + k0 + kk) = *(int4*)&t[n * 72 + kk];
  *(int4*)(WT + (size_t)(n0 + n) * K + k0 + kk + 8) =
      *(int4*)&t[n * 72 + kk + 8];
}

// ---------------------------------------------------------------------------
// GEMM1: fused = xb[2048][4096](bf16) * WT^T + bqkv, RoPE + head-split
// epilogue. 256x256 tile, BK=64, 8 waves (2M x 4N), dbuf 128KiB LDS.
//
// K-loop = the round-1 2-phase schedule (best measured: 131.2us, MfmaUtil
// 33%). Rounds 2-3's 4-phase and counted-vmcnt variants were 137-140us;
// round-4's 4-wave/128x128-per-wave big-tile SPILLED (VGPR capped at 256,
// WRITE_SIZE 24->83MB, 397us) — acc footprint must stay <=64 f32x4/lane.
// Schedule per K-tile: vmcnt(0) -> s_barrier -> issue next tile's 8
// global_load_lds -> 64 MFMA (compiler-scheduled fine-grained lgkmcnt).
// Epilogue RoPE uses the precomputed rtab (this round's single change).
// Bank conflicts: per-row XOR chunk swizzle on pre-swizzled global source
// (LDS dest linear for global_load_lds) + same XOR on ds_read chunk.
// ---------------------------------------------------------------------------
__global__ __launch_bounds__(512, 2) void gemm1_kernel(
    const unsigned short* __restrict__ xb,
    const unsigned short* __restrict__ WT, const float* __restrict__ bias,
    const float2* __restrict__ rtab, unsigned short* __restrict__ Qb,
    unsigned short* __restrict__ Kb, unsigned short* __restrict__ Vt) {
  // [slot][ A 256x64 | B 256x64 ] bf16 = 2 x 64KiB = 128KiB
  __shared__ unsigned short sm[2][32768];

  const int tid = threadIdx.x;
  const int bn = blockIdx.x, bm = blockIdx.y;
  const int lane = tid & 63, wave = tid >> 6;
  const int lrow = lane & 15, quad = lane >> 4;
  const int wrow = wave >> 2, wcol = wave & 3;  // 2M x 4N wave grid

  f32x4 acc[8][4];
#pragma unroll
  for (int i = 0; i < 8; ++i)
#pragma unroll
    for (int j = 0; j < 4; ++j) {
      f32x4 z = {0.f, 0.f, 0.f, 0.f};
      acc[i][j] = z;
    }

  // staging invariants: each copy = 64 rows over 8 waves (8 rows/wave).
  const int lr8 = lane >> 3, lc8 = lane & 7;
  const int baser = wave * 8 + lr8;                 // tile row 0..63 (+c*64)
  const size_t swz = (size_t)((lc8 ^ (baser & 7)) << 3);  // chunk pre-swizzle
  const unsigned short* sA = xb + (size_t)(bm * 256 + baser) * MDIM + swz;
  const unsigned short* sB = WT + (size_t)(bn * 256 + baser) * MDIM + swz;

  auto stage = [&](int slot, int k0) {
#pragma unroll
    for (int c = 0; c < 4; ++c) {
      unsigned short* dA = &sm[slot][(c * 64 + wave * 8) * 64];
      unsigned short* dB = &sm[slot][16384 + (c * 64 + wave * 8) * 64];
      async_copy16(sA + (size_t)c * 64 * MDIM + k0, dA);
      async_copy16(sB + (size_t)c * 64 * MDIM + k0, dB);
    }
  };

  // fragment-read invariants (row&7 == lrow&7 for all frags)
  const int arow = wrow * 128 + lrow;
  const int brow = wcol * 64 + lrow;
  const int co0 = (quad ^ (lrow & 7)) << 3;
  const int co1 = ((4 + quad) ^ (lrow & 7)) << 3;

  stage(0, 0);  // prologue: K-tile 0 -> slot 0

  for (int kt = 0; kt < 64; ++kt) {
    const int p = kt & 1;
    // own 8 copies of tile kt are the only outstanding VMEM ops; each wave
    // drains ITS copies before the barrier => after barrier all landed.
    asm volatile("s_waitcnt vmcnt(0)" ::: "memory");
    __builtin_amdgcn_s_barrier();  // also: all waves done reading slot p^1
    __builtin_amdgcn_sched_barrier(0);

    if (kt < 63) stage(p ^ 1, (kt + 1) << 6);  // flies under this compute

    const unsigned short* Asl = &sm[p][0];
    const unsigned short* Bsl = &sm[p][16384];
    __builtin_amdgcn_s_setprio(1);
#pragma unroll
    for (int kk = 0; kk < 2; ++kk) {
      const int co = kk ? co1 : co0;
      bf16x8 bfr[4];
#pragma unroll
      for (int j = 0; j < 4; ++j)
        bfr[j] = *(const bf16x8*)&Bsl[(brow + j * 16) * 64 + co];
#pragma unroll
      for (int i = 0; i < 8; ++i) {
        bf16x8 af = *(const bf16x8*)&Asl[(arow + i * 16) * 64 + co];
#pragma unroll
        for (int j = 0; j < 4; ++j)
          acc[i][j] = __builtin_amdgcn_mfma_f32_16x16x32_bf16(
              af, bfr[j], acc[i][j], 0, 0, 0);
      }
    }
    __builtin_amdgcn_s_setprio(0);
  }
  __syncthreads();  // K-loop reads done before Ct overwrites staging LDS

  // ---- epilogue: two 128-col halves; Ct[256][132] reuses staging LDS ----
  unsigned short* Ct = &sm[0][0];
#pragma unroll 1
  for (int h = 0; h < 2; ++h) {
    const int slot = 2 * bn + h;  // 0..31 Q, 32..39 K, 40..47 V
    if ((wcol >> 1) == h) {       // waves owning this col half write acc
#pragma unroll
      for (int i = 0; i < 8; ++i)
#pragma unroll
        for (int j = 0; j < 4; ++j) {
          int lc = (wcol & 1) * 64 + j * 16 + lrow;
          float bv = bias[slot * 128 + lc];
#pragma unroll
          for (int r = 0; r < 4; ++r) {
            int lrw = wrow * 128 + i * 16 + quad * 4 + r;
            Ct[lrw * 132 + lc] = f2b(acc[i][j][r] + bv);
          }
        }
    }
    __syncthreads();

    if (slot < 40) {
#pragma unroll 4
      for (int it = 0; it < 32; ++it) {
        int row = it * 8 + wave;  // 0..255
        int d = lane;
        float x1 = b2f(Ct[row * 132 + d]);
        float x2 = b2f(Ct[row * 132 + d + 64]);
        int s = bm * 256 + row;
        float2 cs = rtab[s * 64 + d];  // (cos, sin) precomputed
        float o1 = x1 * cs.x - x2 * cs.y;
        float o2 = x2 * cs.x + x1 * cs.y;
        unsigned short* dst;
        if (slot < 32)
          dst = Qb + ((size_t)slot * S_LEN + s) * HD;
        else
          dst = Kb + ((size_t)(slot - 32) * S_LEN + s) * HD;
        dst[d] = f2b(o1);
        dst[d + 64] = f2b(o2);
      }
    } else {
      // V: write transposed Vt[g][d][s], coalesced along s
      const int g = slot - 40;
      unsigned short* Vtg = Vt + (size_t)g * HD * S_LEN;  // [128][2048]
      const int dp = tid >> 3;         // d-pair 0..63
      const int sq = (tid & 7) << 5;   // s-eighth 0,32,..,224
      unsigned short buf0[32], buf1[32];
#pragma unroll
      for (int i = 0; i < 32; ++i) {
        unsigned int w = *(const unsigned int*)&Ct[(sq + i) * 132 + 2 * dp];
        buf0[i] = (unsigned short)(w & 0xffffu);
        buf1[i] = (unsigned short)(w >> 16);
      }
      const int s0 = bm * 256 + sq;
#pragma unroll
      for (int c = 0; c < 2; ++c) {
        unsigned short* dst = Vtg + (size_t)(2 * dp + c) * S_LEN + s0;
        const unsigned short* b = c ? buf1 : buf0;
#pragma unroll
        for (int q4 = 0; q4 < 4; ++q4)
          *(int4*)(dst + q4 * 8) = *(const int4*)(b + q4 * 8);
      }
    }
    __syncthreads();  // pass-h reads done before pass h+1 overwrites Ct
  }
}

// ---------------------------------------------------------------------------
// GEMM2: out = attnb[2048][4096](bf16) * WoT^T + bo (f32 out).
// BM=128 x BN=256 (grid 16x16 = 256 blocks = 1/CU), BK=64, 8 waves (2M x 4N,
// 64x64 per wave), dbuf 96KiB LDS, 2-phase-per-K-tile schedule.
// ---------------------------------------------------------------------------
__global__ __launch_bounds__(512, 2) void gemm2_kernel(
    const unsigned short* __restrict__ Ab16,
    const unsigned short* __restrict__ BT, const float* __restrict__ bias,
    float* __restrict__ C) {
  // [slot][ A 128x64 | B 256x64 ] bf16 = 2 x 48KiB = 96KiB
  __shared__ unsigned short sm[2][24576];

  const int tid = threadIdx.x;
  const int bn = blockIdx.x, bm = blockIdx.y;  // bn: N/256, bm: M/128
  const int lane = tid & 63, wave = tid >> 6;
  const int lrow = lane & 15, quad = lane >> 4;
  const int wrow = wave >> 2, wcol = wave & 3;  // 2M x 4N wave grid

  f32x4 acc[4][4];
#pragma unroll
  for (int i = 0; i < 4; ++i)
#pragma unroll
    for (int j = 0; j < 4; ++j) {
      f32x4 z = {0.f, 0.f, 0.f, 0.f};
      acc[i][j] = z;
    }

  const int lr8 = lane >> 3, lc8 = lane & 7;
  const int baser = wave * 8 + lr8;
  const size_t swz = (size_t)((lc8 ^ (baser & 7)) << 3);
  const unsigned short* sA = Ab16 + (size_t)(bm * 128 + baser) * MDIM + swz;
  const unsigned short* sB = BT + (size_t)(bn * 256 + baser) * MDIM + swz;

  auto stageA2 = [&](int slot, int k0) {
#pragma unroll
    for (int c = 0; c < 2; ++c)
      async_copy16(sA + (size_t)c * 64 * MDIM + k0,
                   &sm[slot][(c * 64 + wave * 8) * 64]);
  };
  auto stageB1 = [&](int slot, int k0, int c) {
    async_copy16(sB + (size_t)c * 64 * MDIM + k0,
                 &sm[slot][8192 + (c * 64 + wave * 8) * 64]);
  };

  const int arow = wrow * 64 + lrow;
  const int brow = wcol * 64 + lrow;
  const int co0 = (quad ^ (lrow & 7)) << 3;
  const int co1 = ((4 + quad) ^ (lrow & 7)) << 3;

  // prologue: K-tile 0 -> slot 0
  stageA2(0, 0);
  stageB1(0, 0, 0);
  stageB1(0, 0, 1);
  stageB1(0, 0, 2);
  stageB1(0, 0, 3);

#pragma unroll 1
  for (int kt = 0; kt < 64; ++kt) {
    const int p = kt & 1;
    asm volatile("s_waitcnt vmcnt(0)" ::: "memory");
    __builtin_amdgcn_s_barrier();
    __builtin_amdgcn_sched_barrier(0);

    const unsigned short* Asl = &sm[p][0];
    const unsigned short* Bsl = &sm[p][8192];
    const int kn0 = (kt + 1) << 6;
    const bool pref = kt < 63;
    bf16x8 bfr[4], af[4];

    // ---- P0: kk=0 (reads 4B+4A, stage A c0..1 + B c0) ----
#pragma unroll
    for (int j = 0; j < 4; ++j)
      bfr[j] = *(const bf16x8*)&Bsl[(brow + j * 16) * 64 + co0];
#pragma unroll
    for (int i = 0; i < 4; ++i)
      af[i] = *(const bf16x8*)&Asl[(arow + i * 16) * 64 + co0];
    if (pref) {
      stageA2(p ^ 1, kn0);
      stageB1(p ^ 1, kn0, 0);
    }
    __builtin_amdgcn_s_barrier();
    asm volatile("s_waitcnt lgkmcnt(0)" ::: "memory");
    __builtin_amdgcn_sched_barrier(0);
    __builtin_amdgcn_s_setprio(1);
#pragma unroll
    for (int i = 0; i < 4; ++i)
#pragma unroll
      for (int j = 0; j < 4; ++j)
        acc[i][j] = __builtin_amdgcn_mfma_f32_16x16x32_bf16(af[i], bfr[j],
                                                            acc[i][j], 0, 0, 0);
    __builtin_amdgcn_s_setprio(0);
    __builtin_amdgcn_s_barrier();

    // ---- P1: kk=1 (reads 4B+4A, stage B c1..3; no trailing bar) ----
#pragma unroll
    for (int j = 0; j < 4; ++j)
      bfr[j] = *(const bf16x8*)&Bsl[(brow + j * 16) * 64 + co1];
#pragma unroll
    for (int i = 0; i < 4; ++i)
      af[i] = *(const bf16x8*)&Asl[(arow + i * 16) * 64 + co1];
    if (pref) {
      stageB1(p ^ 1, kn0, 1);
      stageB1(p ^ 1, kn0, 2);
      stageB1(p ^ 1, kn0, 3);
    }
    __builtin_amdgcn_s_barrier();
    asm volatile("s_waitcnt lgkmcnt(0)" ::: "memory");
    __builtin_amdgcn_sched_barrier(0);
    __builtin_amdgcn_s_setprio(1);
#pragma unroll
    for (int i = 0; i < 4; ++i)
#pragma unroll
      for (int j = 0; j < 4; ++j)
        acc[i][j] = __builtin_amdgcn_mfma_f32_16x16x32_bf16(af[i], bfr[j],
                                                            acc[i][j], 0, 0, 0);
    __builtin_amdgcn_s_setprio(0);
  }

  // epilogue: direct f32 store with bias
#pragma unroll
  for (int i = 0; i < 4; ++i)
#pragma unroll
    for (int j = 0; j < 4; ++j) {
      int gcol = bn * 256 + wcol * 64 + j * 16 + lrow;
      float bv = bias[gcol];
#pragma unroll
      for (int r = 0; r < 4; ++r) {
        int grow = bm * 128 + wrow * 64 + i * 16 + quad * 4 + r;
        C[(size_t)grow * MDIM + gcol] = acc[i][j][r] + bv;
      }
    }
}

// ---------------------------------------------------------------------------
// Flash attention, causal, GQA. Fixed-max softmax (scores bounded; exp(s-12)
// cannot overflow, o/l unchanged). Q in registers. K/V double-buffered LDS
// via global_load_lds with XOR-swizzled layout (pre-swizzled global source,
// linear LDS dest). One vmcnt(0)+barrier per KV-tile; prefetch issued after
// the barrier flies under the whole compute phase. Ps fence: lgkmcnt only.
// Row-sums via ones-MFMA. 1D LPT grid.
// ---------------------------------------------------------------------------
__device__ __forceinline__ void stage_kv(const unsigned short* __restrict__ Kg,
                                         const unsigned short* __restrict__ Vg,
                                         int jtile, unsigned short* KsBuf,
                                         unsigned short* VsBuf, int wv,
                                         int lane) {
  const unsigned short* kg = Kg + (size_t)jtile * 64 * HD;
  const unsigned short* vg = Vg + jtile * 64;
#pragma unroll
  for (int it = 0; it < 4; ++it) {
    // K: 4 rows x 256B per copy; lane -> row base+(l>>4), chunk l&15
    int kr = wv * 16 + it * 4 + (lane >> 4);
    async_copy16(kg + (size_t)kr * HD + (((lane & 15) ^ (kr & 7)) << 3),
                 KsBuf + (wv * 16 + it * 4) * 128);
    // V: 8 rows x 128B per copy; lane -> row base+(l>>3), chunk l&7
    int vr = wv * 32 + it * 8 + (lane >> 3);
    async_copy16(vg + (size_t)vr * S_LEN + (((lane & 7) ^ (vr & 7)) << 3),
                 VsBuf + (wv * 32 + it * 8) * 64);
  }
}

__global__ __launch_bounds__(256, 2) void flash_kernel(
    const unsigned short* __restrict__ Qb, const unsigned short* __restrict__ Kb,
    const unsigned short* __restrict__ Vt, unsigned short* __restrict__ attnb) {
  __shared__ __align__(16) unsigned short Ks[2][64 * 128];  // [krow][d] swz
  __shared__ __align__(16) unsigned short Vs[2][128 * 64];  // [d][kvpos] swz
  __shared__ __align__(16) unsigned short Ps[64 * 72];      // [qrow][kvpos]

  const int tid = threadIdx.x;
  const int bid = blockIdx.x;
  const int h = bid & 31;
  const int qt = 31 - (bid >> 5);  // heavy tiles dispatch first (LPT)
  const int g = h >> 2;
  const int wv = tid >> 6, lane = tid & 63;
  const int lrow = lane & 15, quad = lane >> 4;
  const float scale = 0.08838834764831845f;  // 1/sqrt(128)

  const unsigned short* Qg = Qb + ((size_t)h * S_LEN + qt * 64) * HD;
  bf16x8 qf[4];
#pragma unroll
  for (int ks = 0; ks < 4; ++ks)
    qf[ks] = *(const bf16x8*)(Qg + (size_t)(wv * 16 + lrow) * HD + ks * 32 +
                              quad * 8);

  // all-ones bf16 B-fragment for row-sum MFMA
  bf16x8 ones;
#pragma unroll
  for (int i = 0; i < 8; ++i) ones[i] = (short)0x3F80;

  const unsigned short* Kg = Kb + (size_t)g * S_LEN * HD;   // [s][d]
  const unsigned short* Vg = Vt + (size_t)g * HD * S_LEN;   // [d][s]

  f32x4 l_acc = {0.f, 0.f, 0.f, 0.f};
  f32x4 o_acc[8];
#pragma unroll
  for (int jc = 0; jc < 8; ++jc) {
    f32x4 z = {0.f, 0.f, 0.f, 0.f};
    o_acc[jc] = z;
  }

  // prologue: stage tile 0 into buffer 0
  stage_kv(Kg, Vg, 0, &Ks[0][0], &Vs[0][0], wv, lane);

  for (int jt = 0; jt <= qt; ++jt) {
    const int cb = jt & 1;
    // own copies of tile jt are the only outstanding VMEM ops
    asm volatile("s_waitcnt vmcnt(0)" ::: "memory");
    __builtin_amdgcn_s_barrier();  // all waves' copies landed; all waves
                                   // done reading buf cb from iter jt-2
    __builtin_amdgcn_sched_barrier(0);

    if (jt < qt)  // prefetch next tile; flies under this iter's compute
      stage_kv(Kg, Vg, jt + 1, &Ks[cb ^ 1][0], &Vs[cb ^ 1][0], wv, lane);

    // S = Q K^T (wave's 16 rows x 64 cols)
    f32x4 s_acc[4];
#pragma unroll
    for (int j = 0; j < 4; ++j) {
      f32x4 z = {0.f, 0.f, 0.f, 0.f};
      s_acc[j] = z;
    }
#pragma unroll
    for (int ks = 0; ks < 4; ++ks)
#pragma unroll
      for (int j = 0; j < 4; ++j) {
        int row = j * 16 + lrow;
        bf16x8 bk = *(const bf16x8*)&Ks[cb][row * 128 +
                                           (((ks * 4 + quad) ^ (row & 7)) << 3)];
        s_acc[j] = __builtin_amdgcn_mfma_f32_16x16x32_bf16(qf[ks], bk,
                                                           s_acc[j], 0, 0, 0);
      }

    // fixed-max softmax: p = exp(s*scale - 12); mask only on diagonal tile
    if (jt == qt) {
#pragma unroll
      for (int r = 0; r < 4; ++r) {
        int grow = qt * 64 + wv * 16 + quad * 4 + r;
#pragma unroll
        for (int j = 0; j < 4; ++j) {
          int gcol = jt * 64 + j * 16 + lrow;
          float p =
              (gcol <= grow) ? __expf(s_acc[j][r] * scale - 12.0f) : 0.f;
          Ps[(wv * 16 + quad * 4 + r) * 72 + j * 16 + lrow] = f2b(p);
        }
      }
    } else {
#pragma unroll
      for (int r = 0; r < 4; ++r)
#pragma unroll
        for (int j = 0; j < 4; ++j) {
          float p = __expf(s_acc[j][r] * scale - 12.0f);
          Ps[(wv * 16 + quad * 4 + r) * 72 + j * 16 + lrow] = f2b(p);
        }
    }
    // Ps band is wave-private: LDS drain only (must NOT drain vmcnt — the
    // next tile's global_load_lds copies are in flight)
    asm volatile("s_waitcnt lgkmcnt(0)" ::: "memory");
    __builtin_amdgcn_sched_barrier(0);

    // O += P V (16 rows x 128 cols, K=64); l += P * ones
#pragma unroll
    for (int kk = 0; kk < 2; ++kk) {
      bf16x8 ap =
          *(const bf16x8*)&Ps[(wv * 16 + lrow) * 72 + kk * 32 + 8 * quad];
      l_acc = __builtin_amdgcn_mfma_f32_16x16x32_bf16(ap, ones, l_acc, 0, 0, 0);
#pragma unroll
      for (int jc = 0; jc < 8; ++jc) {
        int row = jc * 16 + lrow;
        bf16x8 bv = *(const bf16x8*)&Vs[cb][row * 64 +
                                            (((kk * 4 + quad) ^ (row & 7)) << 3)];
        o_acc[jc] = __builtin_amdgcn_mfma_f32_16x16x32_bf16(ap, bv, o_acc[jc],
                                                            0, 0, 0);
      }
    }
    __builtin_amdgcn_s_barrier();  // all waves done reading buf cb before
                                   // iter jt+1 issues copies into buf cb
  }

  // epilogue: O / l -> attnb[s][h*128+d] (bf16)
#pragma unroll
  for (int r = 0; r < 4; ++r) {
    float inv_l = 1.0f / l_acc[r];
    int row = qt * 64 + wv * 16 + quad * 4 + r;
#pragma unroll
    for (int jc = 0; jc < 8; ++jc) {
      int col = jc * 16 + lrow;
      attnb[(size_t)row * MDIM + h * HD + col] = f2b(o_acc[jc][r] * inv_l);
    }
  }
}

// ---------------------------------------------------------------------------
extern "C" void kernel_launch(void* const* d_in, const int* in_sizes, int n_in,
                              void* d_out, int out_size, void* d_ws,
                              size_t ws_size, hipStream_t stream) {
  const float* x = (const float*)d_in[0];
  const float* Wqkv = (const float*)d_in[1];
  const float* bqkv = (const float*)d_in[2];
  const float* Wo = (const float*)d_in[3];
  const float* bo = (const float*)d_in[4];
  float* out = (float*)d_out;

  unsigned char* ws = (unsigned char*)d_ws;
  // region A [0, 50331648): phase1 = WT (6144x4096 bf16);
  //                         phase2 = WoT (33554432) + attnb (16777216)
  unsigned short* WT = (unsigned short*)ws;
  unsigned short* WoT = (unsigned short*)ws;
  unsigned short* attnb = (unsigned short*)(ws + 33554432);
  // region B: Q/K head-major bf16, V transposed [g][d][s]
  unsigned short* Qb = (unsigned short*)(ws + 50331648);  // 32*2048*128
  unsigned short* Kb = (unsigned short*)(ws + 67108864);  // 8*2048*128
  unsigned short* Vt = (unsigned short*)(ws + 71303168);  // 8*128*2048
  // d_out scratch: xb (bf16 x) in [0,16MB); RoPE table in [16MB,17MB).
  // Both consumed before gemm2 overwrites d_out with the final output.
  unsigned short* xb = (unsigned short*)d_out;
  float2* rtab = (float2*)((unsigned char*)d_out + 16777216);

  // 0. x f32 -> bf16 (into d_out scratch) + RoPE cos/sin table
  convert_x<<<(S_LEN * MDIM / 8) / 256, 256, 0, stream>>>(x, xb);
  rope_table<<<(S_LEN * 64) / 256, 256, 0, stream>>>(rtab);
  // 1. Wqkv [4096][6144] f32 -> WT [6144][4096] bf16
  transpose_convert<<<dim3(NFUSED / 64, MDIM / 64), 256, 0, stream>>>(
      Wqkv, WT, MDIM, NFUSED);
  // 2. QKV GEMM with fused bias + RoPE + head split (V transposed)
  gemm1_kernel<<<dim3(NFUSED / 256, S_LEN / 256), 512, 0, stream>>>(
      xb, WT, bqkv, rtab, Qb, Kb, Vt);
  // 3. Wo [4096][4096] f32 -> WoT [4096][4096] bf16 (reuses WT region)
  transpose_convert<<<dim3(MDIM / 64, MDIM / 64), 256, 0, stream>>>(Wo, WoT,
                                                                    MDIM, MDIM);
  // 4. causal GQA flash attention -> attnb bf16 (1D LPT grid)
  flash_kernel<<<S_LEN / 64 * NHEADS, 256, 0, stream>>>(Qb, Kb, Vt, attnb);
  // 5. output projection (overwrites xb scratch region of d_out)
  gemm2_kernel<<<dim3(MDIM / 256, S_LEN / 128), 512, 0, stream>>>(attnb, WoT,
                                                                  bo, out);
}

// Round 7
// 484.448 us; speedup vs baseline: 1.5643x; 1.0065x over previous
//
#include <hip/hip_runtime.h>
#include <hip/hip_bf16.h>
#include <math.h>

#define S_LEN  2048
#define MDIM   4096
#define NHEADS 32
#define NKV    8
#define HD     128
#define KVDIM  1024
#define NFUSED (MDIM + 2 * KVDIM) /* 6144 */

typedef short bf16x8 __attribute__((ext_vector_type(8)));
typedef float f32x4 __attribute__((ext_vector_type(4)));
typedef float f32x16 __attribute__((ext_vector_type(16)));

__device__ __forceinline__ unsigned short f2b(float f) {
  union { float f; unsigned int u; } v; v.f = f;
  unsigned int r = v.u + 0x7FFFu + ((v.u >> 16) & 1u);
  return (unsigned short)(r >> 16);
}
__device__ __forceinline__ float b2f(unsigned short h) {
  union { unsigned int u; float f; } v; v.u = ((unsigned int)h) << 16;
  return v.f;
}

// async global->LDS, 16B per lane; lds dest = wave-uniform base + lane*16
__device__ __forceinline__ void async_copy16(const void* g, void* l) {
  __builtin_amdgcn_global_load_lds(
      (const __attribute__((address_space(1))) unsigned int*)g,
      (__attribute__((address_space(3))) unsigned int*)l, 16, 0, 0);
}

// ---------------------------------------------------------------------------
// x f32 -> bf16 (one thread per 8 elements)
// ---------------------------------------------------------------------------
__global__ __launch_bounds__(256) void convert_x(
    const float* __restrict__ src, unsigned short* __restrict__ dst) {
  size_t i = (size_t)blockIdx.x * 256 + threadIdx.x;
  const float4 a = ((const float4*)src)[2 * i];
  const float4 b = ((const float4*)src)[2 * i + 1];
  unsigned short o[8] = {f2b(a.x), f2b(a.y), f2b(a.z), f2b(a.w),
                         f2b(b.x), f2b(b.y), f2b(b.z), f2b(b.w)};
  *(int4*)(dst + 8 * i) = *(const int4*)o;
}

// ---------------------------------------------------------------------------
// RoPE table: rtab[s*64+d] = (cos, sin)(s * 50000^(-d/64)). One-time, ~4us.
// ---------------------------------------------------------------------------
__global__ __launch_bounds__(256) void rope_table(float2* __restrict__ rtab) {
  int t = blockIdx.x * 256 + threadIdx.x;  // 0..131071
  int s = t >> 6, d = t & 63;
  float inv_freq = __expf(-0.16905903569f * (float)d);  // 50000^(-d/64)
  float ang = (float)s * inv_freq;
  rtab[t] = make_float2(cosf(ang), sinf(ang));
}

// ---------------------------------------------------------------------------
// Transpose + convert: W [K][N] f32 -> WT [N][K] bf16. 64x64 tiles.
// ---------------------------------------------------------------------------
__global__ __launch_bounds__(256) void transpose_convert(
    const float* __restrict__ W, unsigned short* __restrict__ WT, int K,
    int N) {
  __shared__ unsigned short t[64 * 72];  // [n][k], pad 64->72
  const int k0 = blockIdx.y << 6, n0 = blockIdx.x << 6;
  const int tid = threadIdx.x;
#pragma unroll
  for (int it = 0; it < 4; ++it) {
    int idx = it * 256 + tid;          // 0..1023
    int r = idx & 63;                  // k row
    int c = ((idx >> 6) & 15) << 2;    // n col group
    const float4 v = *(const float4*)(W + (size_t)(k0 + r) * N + n0 + c);
    t[(c + 0) * 72 + r] = f2b(v.x);
    t[(c + 1) * 72 + r] = f2b(v.y);
    t[(c + 2) * 72 + r] = f2b(v.z);
    t[(c + 3) * 72 + r] = f2b(v.w);
  }
  __syncthreads();
  const int n = tid >> 2, kk = (tid & 3) << 4;
  *(int4*)(WT + (size_t)(n0 + n) * K + k0 + kk) = *(int4*)&t[n * 72 + kk];
  *(int4*)(WT + (size_t)(n0 + n) * K + k0 + kk + 8) =
      *(int4*)&t[n * 72 + kk + 8];
}

// ---------------------------------------------------------------------------
// GEMM1: fused = xb[2048][4096](bf16) * WT^T + bqkv, RoPE + head-split
// epilogue. 256x256 tile, BK=64, 8 waves (2M x 4N), dbuf 128KiB LDS.
//
// K-loop: round-1 schedule (single vmcnt(0)+barrier per K-tile; 3 schedule
// rewrites all landed within +-5% => not schedule-bound) but with
// **32x32x16 MFMA**: same FLOPs at 2495 TF ceiling vs 2075 for 16x16x32
// (m119/m06) -> MFMA pipe 2480->2066 cyc/K-tile, and half the instruction
// count. LDS fragment traffic unchanged. Layouts: A lane holds
// A[l&31][(l>>5)*8+j]; B^T row n=l&31, k=(l>>5)*8+j (same 16B chunk reads
// from the swizzled LDS, chunk (2t+lh)^(row&7)); C/D col=lane&31,
// row=(reg&3)+8*(reg>>2)+4*(lane>>5) [guide m74/m101-verified].
// acc = f32x16[4][2] (128 f32/lane), statically indexed (rule #20).
// Bank conflicts: per-row XOR chunk swizzle on pre-swizzled global source
// (LDS dest linear for global_load_lds) + same XOR on ds_read chunk.
// ---------------------------------------------------------------------------
__global__ __launch_bounds__(512, 2) void gemm1_kernel(
    const unsigned short* __restrict__ xb,
    const unsigned short* __restrict__ WT, const float* __restrict__ bias,
    const float2* __restrict__ rtab, unsigned short* __restrict__ Qb,
    unsigned short* __restrict__ Kb, unsigned short* __restrict__ Vt) {
  // [slot][ A 256x64 | B 256x64 ] bf16 = 2 x 64KiB = 128KiB
  __shared__ unsigned short sm[2][32768];

  const int tid = threadIdx.x;
  const int bn = blockIdx.x, bm = blockIdx.y;
  const int lane = tid & 63, wave = tid >> 6;
  const int l31 = lane & 31, lh = lane >> 5;
  const int wrow = wave >> 2, wcol = wave & 3;  // 2M x 4N wave grid

  f32x16 acc[4][2];
#pragma unroll
  for (int i = 0; i < 4; ++i)
#pragma unroll
    for (int j = 0; j < 2; ++j)
#pragma unroll
      for (int r = 0; r < 16; ++r) acc[i][j][r] = 0.f;

  // staging invariants: each copy = 64 rows over 8 waves (8 rows/wave).
  const int lr8 = lane >> 3, lc8 = lane & 7;
  const int baser = wave * 8 + lr8;                 // tile row 0..63 (+c*64)
  const size_t swz = (size_t)((lc8 ^ (baser & 7)) << 3);  // chunk pre-swizzle
  const unsigned short* sA = xb + (size_t)(bm * 256 + baser) * MDIM + swz;
  const unsigned short* sB = WT + (size_t)(bn * 256 + baser) * MDIM + swz;

  auto stage = [&](int slot, int k0) {
#pragma unroll
    for (int c = 0; c < 4; ++c) {
      unsigned short* dA = &sm[slot][(c * 64 + wave * 8) * 64];
      unsigned short* dB = &sm[slot][16384 + (c * 64 + wave * 8) * 64];
      async_copy16(sA + (size_t)c * 64 * MDIM + k0, dA);
      async_copy16(sB + (size_t)c * 64 * MDIM + k0, dB);
    }
  };

  // fragment-read invariants: rows rm/rn have (row&7) == (l31&7)
  const int arow0 = wrow * 128 + l31;  // + i*32
  const int brow0 = wcol * 64 + l31;   // + jj*32
  const int cswz = l31 & 7;

  stage(0, 0);  // prologue: K-tile 0 -> slot 0

  for (int kt = 0; kt < 64; ++kt) {
    const int p = kt & 1;
    // own 8 copies of tile kt are the only outstanding VMEM ops; each wave
    // drains ITS copies before the barrier => after barrier all landed.
    asm volatile("s_waitcnt vmcnt(0)" ::: "memory");
    __builtin_amdgcn_s_barrier();  // also: all waves done reading slot p^1
    __builtin_amdgcn_sched_barrier(0);

    if (kt < 63) stage(p ^ 1, (kt + 1) << 6);  // flies under this compute

    const unsigned short* Asl = &sm[p][0];
    const unsigned short* Bsl = &sm[p][16384];
    __builtin_amdgcn_s_setprio(1);
#pragma unroll
    for (int t = 0; t < 4; ++t) {  // k-step of 16
      const int co = ((2 * t + lh) ^ cswz) << 3;
      bf16x8 bfr[2], af[4];
#pragma unroll
      for (int jj = 0; jj < 2; ++jj)
        bfr[jj] = *(const bf16x8*)&Bsl[(brow0 + jj * 32) * 64 + co];
#pragma unroll
      for (int i = 0; i < 4; ++i)
        af[i] = *(const bf16x8*)&Asl[(arow0 + i * 32) * 64 + co];
#pragma unroll
      for (int i = 0; i < 4; ++i)
#pragma unroll
        for (int jj = 0; jj < 2; ++jj)
          acc[i][jj] = __builtin_amdgcn_mfma_f32_32x32x16_bf16(
              af[i], bfr[jj], acc[i][jj], 0, 0, 0);
    }
    __builtin_amdgcn_s_setprio(0);
  }
  __syncthreads();  // K-loop reads done before Ct overwrites staging LDS

  // ---- epilogue: two 128-col halves; Ct[256][132] reuses staging LDS ----
  unsigned short* Ct = &sm[0][0];
#pragma unroll 1
  for (int h = 0; h < 2; ++h) {
    const int slot = 2 * bn + h;  // 0..31 Q, 32..39 K, 40..47 V
    if ((wcol >> 1) == h) {       // waves owning this col half write acc
#pragma unroll
      for (int i = 0; i < 4; ++i)
#pragma unroll
        for (int jj = 0; jj < 2; ++jj) {
          int lc = (wcol & 1) * 64 + jj * 32 + l31;
          float bv = bias[slot * 128 + lc];
#pragma unroll
          for (int r = 0; r < 16; ++r) {
            int lrw = wrow * 128 + i * 32 + (r & 3) + 8 * (r >> 2) + 4 * lh;
            Ct[lrw * 132 + lc] = f2b(acc[i][jj][r] + bv);
          }
        }
    }
    __syncthreads();

    if (slot < 40) {
#pragma unroll 4
      for (int it = 0; it < 32; ++it) {
        int row = it * 8 + wave;  // 0..255
        int d = lane;
        float x1 = b2f(Ct[row * 132 + d]);
        float x2 = b2f(Ct[row * 132 + d + 64]);
        int s = bm * 256 + row;
        float2 cs = rtab[s * 64 + d];  // (cos, sin) precomputed
        float o1 = x1 * cs.x - x2 * cs.y;
        float o2 = x2 * cs.x + x1 * cs.y;
        unsigned short* dst;
        if (slot < 32)
          dst = Qb + ((size_t)slot * S_LEN + s) * HD;
        else
          dst = Kb + ((size_t)(slot - 32) * S_LEN + s) * HD;
        dst[d] = f2b(o1);
        dst[d + 64] = f2b(o2);
      }
    } else {
      // V: write transposed Vt[g][d][s], coalesced along s
      const int g = slot - 40;
      unsigned short* Vtg = Vt + (size_t)g * HD * S_LEN;  // [128][2048]
      const int dp = tid >> 3;         // d-pair 0..63
      const int sq = (tid & 7) << 5;   // s-eighth 0,32,..,224
      unsigned short buf0[32], buf1[32];
#pragma unroll
      for (int i = 0; i < 32; ++i) {
        unsigned int w = *(const unsigned int*)&Ct[(sq + i) * 132 + 2 * dp];
        buf0[i] = (unsigned short)(w & 0xffffu);
        buf1[i] = (unsigned short)(w >> 16);
      }
      const int s0 = bm * 256 + sq;
#pragma unroll
      for (int c = 0; c < 2; ++c) {
        unsigned short* dst = Vtg + (size_t)(2 * dp + c) * S_LEN + s0;
        const unsigned short* b = c ? buf1 : buf0;
#pragma unroll
        for (int q4 = 0; q4 < 4; ++q4)
          *(int4*)(dst + q4 * 8) = *(const int4*)(b + q4 * 8);
      }
    }
    __syncthreads();  // pass-h reads done before pass h+1 overwrites Ct
  }
}

// ---------------------------------------------------------------------------
// GEMM2: out = attnb[2048][4096](bf16) * WoT^T + bo (f32 out).
// BM=128 x BN=256 (grid 16x16 = 256 blocks = 1/CU), BK=64, 8 waves (2M x 4N,
// 64x64 per wave), dbuf 96KiB LDS. This round: 32x32x16 MFMA (same reasons
// as gemm1) + the r1-proven single-barrier-per-K-tile schedule.
// ---------------------------------------------------------------------------
__global__ __launch_bounds__(512, 2) void gemm2_kernel(
    const unsigned short* __restrict__ Ab16,
    const unsigned short* __restrict__ BT, const float* __restrict__ bias,
    float* __restrict__ C) {
  // [slot][ A 128x64 | B 256x64 ] bf16 = 2 x 48KiB = 96KiB
  __shared__ unsigned short sm[2][24576];

  const int tid = threadIdx.x;
  const int bn = blockIdx.x, bm = blockIdx.y;  // bn: N/256, bm: M/128
  const int lane = tid & 63, wave = tid >> 6;
  const int l31 = lane & 31, lh = lane >> 5;
  const int wrow = wave >> 2, wcol = wave & 3;  // 2M x 4N wave grid

  f32x16 acc[2][2];
#pragma unroll
  for (int i = 0; i < 2; ++i)
#pragma unroll
    for (int j = 0; j < 2; ++j)
#pragma unroll
      for (int r = 0; r < 16; ++r) acc[i][j][r] = 0.f;

  const int lr8 = lane >> 3, lc8 = lane & 7;
  const int baser = wave * 8 + lr8;
  const size_t swz = (size_t)((lc8 ^ (baser & 7)) << 3);
  const unsigned short* sA = Ab16 + (size_t)(bm * 128 + baser) * MDIM + swz;
  const unsigned short* sB = BT + (size_t)(bn * 256 + baser) * MDIM + swz;

  auto stage = [&](int slot, int k0) {
#pragma unroll
    for (int c = 0; c < 2; ++c)
      async_copy16(sA + (size_t)c * 64 * MDIM + k0,
                   &sm[slot][(c * 64 + wave * 8) * 64]);
#pragma unroll
    for (int c = 0; c < 4; ++c)
      async_copy16(sB + (size_t)c * 64 * MDIM + k0,
                   &sm[slot][8192 + (c * 64 + wave * 8) * 64]);
  };

  const int arow0 = wrow * 64 + l31;  // + i*32
  const int brow0 = wcol * 64 + l31;  // + jj*32
  const int cswz = l31 & 7;

  stage(0, 0);  // prologue: K-tile 0 -> slot 0

#pragma unroll 1
  for (int kt = 0; kt < 64; ++kt) {
    const int p = kt & 1;
    asm volatile("s_waitcnt vmcnt(0)" ::: "memory");
    __builtin_amdgcn_s_barrier();
    __builtin_amdgcn_sched_barrier(0);

    if (kt < 63) stage(p ^ 1, (kt + 1) << 6);

    const unsigned short* Asl = &sm[p][0];
    const unsigned short* Bsl = &sm[p][8192];
    __builtin_amdgcn_s_setprio(1);
#pragma unroll
    for (int t = 0; t < 4; ++t) {
      const int co = ((2 * t + lh) ^ cswz) << 3;
      bf16x8 bfr[2], af[2];
#pragma unroll
      for (int jj = 0; jj < 2; ++jj)
        bfr[jj] = *(const bf16x8*)&Bsl[(brow0 + jj * 32) * 64 + co];
#pragma unroll
      for (int i = 0; i < 2; ++i)
        af[i] = *(const bf16x8*)&Asl[(arow0 + i * 32) * 64 + co];
#pragma unroll
      for (int i = 0; i < 2; ++i)
#pragma unroll
        for (int jj = 0; jj < 2; ++jj)
          acc[i][jj] = __builtin_amdgcn_mfma_f32_32x32x16_bf16(
              af[i], bfr[jj], acc[i][jj], 0, 0, 0);
    }
    __builtin_amdgcn_s_setprio(0);
  }

  // epilogue: direct f32 store with bias
#pragma unroll
  for (int i = 0; i < 2; ++i)
#pragma unroll
    for (int jj = 0; jj < 2; ++jj) {
      int gcol = bn * 256 + wcol * 64 + jj * 32 + l31;
      float bv = bias[gcol];
#pragma unroll
      for (int r = 0; r < 16; ++r) {
        int grow =
            bm * 128 + wrow * 64 + i * 32 + (r & 3) + 8 * (r >> 2) + 4 * lh;
        C[(size_t)grow * MDIM + gcol] = acc[i][jj][r] + bv;
      }
    }
}

// ---------------------------------------------------------------------------
// Flash attention, causal, GQA. Fixed-max softmax (scores bounded; exp(s-12)
// cannot overflow, o/l unchanged). Q in registers. K/V double-buffered LDS
// via global_load_lds with XOR-swizzled layout (pre-swizzled global source,
// linear LDS dest). One vmcnt(0)+barrier per KV-tile; prefetch issued after
// the barrier flies under the whole compute phase. Ps fence: lgkmcnt only.
// Row-sums via ones-MFMA. 1D LPT grid.
// ---------------------------------------------------------------------------
__device__ __forceinline__ void stage_kv(const unsigned short* __restrict__ Kg,
                                         const unsigned short* __restrict__ Vg,
                                         int jtile, unsigned short* KsBuf,
                                         unsigned short* VsBuf, int wv,
                                         int lane) {
  const unsigned short* kg = Kg + (size_t)jtile * 64 * HD;
  const unsigned short* vg = Vg + jtile * 64;
#pragma unroll
  for (int it = 0; it < 4; ++it) {
    // K: 4 rows x 256B per copy; lane -> row base+(l>>4), chunk l&15
    int kr = wv * 16 + it * 4 + (lane >> 4);
    async_copy16(kg + (size_t)kr * HD + (((lane & 15) ^ (kr & 7)) << 3),
                 KsBuf + (wv * 16 + it * 4) * 128);
    // V: 8 rows x 128B per copy; lane -> row base+(l>>3), chunk l&7
    int vr = wv * 32 + it * 8 + (lane >> 3);
    async_copy16(vg + (size_t)vr * S_LEN + (((lane & 7) ^ (vr & 7)) << 3),
                 VsBuf + (wv * 32 + it * 8) * 64);
  }
}

__global__ __launch_bounds__(256, 2) void flash_kernel(
    const unsigned short* __restrict__ Qb, const unsigned short* __restrict__ Kb,
    const unsigned short* __restrict__ Vt, unsigned short* __restrict__ attnb) {
  __shared__ __align__(16) unsigned short Ks[2][64 * 128];  // [krow][d] swz
  __shared__ __align__(16) unsigned short Vs[2][128 * 64];  // [d][kvpos] swz
  __shared__ __align__(16) unsigned short Ps[64 * 72];      // [qrow][kvpos]

  const int tid = threadIdx.x;
  const int bid = blockIdx.x;
  const int h = bid & 31;
  const int qt = 31 - (bid >> 5);  // heavy tiles dispatch first (LPT)
  const int g = h >> 2;
  const int wv = tid >> 6, lane = tid & 63;
  const int lrow = lane & 15, quad = lane >> 4;
  const float scale = 0.08838834764831845f;  // 1/sqrt(128)

  const unsigned short* Qg = Qb + ((size_t)h * S_LEN + qt * 64) * HD;
  bf16x8 qf[4];
#pragma unroll
  for (int ks = 0; ks < 4; ++ks)
    qf[ks] = *(const bf16x8*)(Qg + (size_t)(wv * 16 + lrow) * HD + ks * 32 +
                              quad * 8);

  // all-ones bf16 B-fragment for row-sum MFMA
  bf16x8 ones;
#pragma unroll
  for (int i = 0; i < 8; ++i) ones[i] = (short)0x3F80;

  const unsigned short* Kg = Kb + (size_t)g * S_LEN * HD;   // [s][d]
  const unsigned short* Vg = Vt + (size_t)g * HD * S_LEN;   // [d][s]

  f32x4 l_acc = {0.f, 0.f, 0.f, 0.f};
  f32x4 o_acc[8];
#pragma unroll
  for (int jc = 0; jc < 8; ++jc) {
    f32x4 z = {0.f, 0.f, 0.f, 0.f};
    o_acc[jc] = z;
  }

  // prologue: stage tile 0 into buffer 0
  stage_kv(Kg, Vg, 0, &Ks[0][0], &Vs[0][0], wv, lane);

  for (int jt = 0; jt <= qt; ++jt) {
    const int cb = jt & 1;
    // own copies of tile jt are the only outstanding VMEM ops
    asm volatile("s_waitcnt vmcnt(0)" ::: "memory");
    __builtin_amdgcn_s_barrier();  // all waves' copies landed; all waves
                                   // done reading buf cb from iter jt-2
    __builtin_amdgcn_sched_barrier(0);

    if (jt < qt)  // prefetch next tile; flies under this iter's compute
      stage_kv(Kg, Vg, jt + 1, &Ks[cb ^ 1][0], &Vs[cb ^ 1][0], wv, lane);

    // S = Q K^T (wave's 16 rows x 64 cols)
    f32x4 s_acc[4];
#pragma unroll
    for (int j = 0; j < 4; ++j) {
      f32x4 z = {0.f, 0.f, 0.f, 0.f};
      s_acc[j] = z;
    }
#pragma unroll
    for (int ks = 0; ks < 4; ++ks)
#pragma unroll
      for (int j = 0; j < 4; ++j) {
        int row = j * 16 + lrow;
        bf16x8 bk = *(const bf16x8*)&Ks[cb][row * 128 +
                                           (((ks * 4 + quad) ^ (row & 7)) << 3)];
        s_acc[j] = __builtin_amdgcn_mfma_f32_16x16x32_bf16(qf[ks], bk,
                                                           s_acc[j], 0, 0, 0);
      }

    // fixed-max softmax: p = exp(s*scale - 12); mask only on diagonal tile
    if (jt == qt) {
#pragma unroll
      for (int r = 0; r < 4; ++r) {
        int grow = qt * 64 + wv * 16 + quad * 4 + r;
#pragma unroll
        for (int j = 0; j < 4; ++j) {
          int gcol = jt * 64 + j * 16 + lrow;
          float p =
              (gcol <= grow) ? __expf(s_acc[j][r] * scale - 12.0f) : 0.f;
          Ps[(wv * 16 + quad * 4 + r) * 72 + j * 16 + lrow] = f2b(p);
        }
      }
    } else {
#pragma unroll
      for (int r = 0; r < 4; ++r)
#pragma unroll
        for (int j = 0; j < 4; ++j) {
          float p = __expf(s_acc[j][r] * scale - 12.0f);
          Ps[(wv * 16 + quad * 4 + r) * 72 + j * 16 + lrow] = f2b(p);
        }
    }
    // Ps band is wave-private: LDS drain only (must NOT drain vmcnt — the
    // next tile's global_load_lds copies are in flight)
    asm volatile("s_waitcnt lgkmcnt(0)" ::: "memory");
    __builtin_amdgcn_sched_barrier(0);

    // O += P V (16 rows x 128 cols, K=64); l += P * ones
#pragma unroll
    for (int kk = 0; kk < 2; ++kk) {
      bf16x8 ap =
          *(const bf16x8*)&Ps[(wv * 16 + lrow) * 72 + kk * 32 + 8 * quad];
      l_acc = __builtin_amdgcn_mfma_f32_16x16x32_bf16(ap, ones, l_acc, 0, 0, 0);
#pragma unroll
      for (int jc = 0; jc < 8; ++jc) {
        int row = jc * 16 + lrow;
        bf16x8 bv = *(const bf16x8*)&Vs[cb][row * 64 +
                                            (((kk * 4 + quad) ^ (row & 7)) << 3)];
        o_acc[jc] = __builtin_amdgcn_mfma_f32_16x16x32_bf16(ap, bv, o_acc[jc],
                                                            0, 0, 0);
      }
    }
    __builtin_amdgcn_s_barrier();  // all waves done reading buf cb before
                                   // iter jt+1 issues copies into buf cb
  }

  // epilogue: O / l -> attnb[s][h*128+d] (bf16)
#pragma unroll
  for (int r = 0; r < 4; ++r) {
    float inv_l = 1.0f / l_acc[r];
    int row = qt * 64 + wv * 16 + quad * 4 + r;
#pragma unroll
    for (int jc = 0; jc < 8; ++jc) {
      int col = jc * 16 + lrow;
      attnb[(size_t)row * MDIM + h * HD + col] = f2b(o_acc[jc][r] * inv_l);
    }
  }
}

// ---------------------------------------------------------------------------
extern "C" void kernel_launch(void* const* d_in, const int* in_sizes, int n_in,
                              void* d_out, int out_size, void* d_ws,
                              size_t ws_size, hipStream_t stream) {
  const float* x = (const float*)d_in[0];
  const float* Wqkv = (const float*)d_in[1];
  const float* bqkv = (const float*)d_in[2];
  const float* Wo = (const float*)d_in[3];
  const float* bo = (const float*)d_in[4];
  float* out = (float*)d_out;

  unsigned char* ws = (unsigned char*)d_ws;
  // region A [0, 50331648): phase1 = WT (6144x4096 bf16);
  //                         phase2 = WoT (33554432) + attnb (16777216)
  unsigned short* WT = (unsigned short*)ws;
  unsigned short* WoT = (unsigned short*)ws;
  unsigned short* attnb = (unsigned short*)(ws + 33554432);
  // region B: Q/K head-major bf16, V transposed [g][d][s]
  unsigned short* Qb = (unsigned short*)(ws + 50331648);  // 32*2048*128
  unsigned short* Kb = (unsigned short*)(ws + 67108864);  // 8*2048*128
  unsigned short* Vt = (unsigned short*)(ws + 71303168);  // 8*128*2048
  // d_out scratch: xb (bf16 x) in [0,16MB); RoPE table in [16MB,17MB).
  // Both consumed before gemm2 overwrites d_out with the final output.
  unsigned short* xb = (unsigned short*)d_out;
  float2* rtab = (float2*)((unsigned char*)d_out + 16777216);

  // 0. x f32 -> bf16 (into d_out scratch) + RoPE cos/sin table
  convert_x<<<(S_LEN * MDIM / 8) / 256, 256, 0, stream>>>(x, xb);
  rope_table<<<(S_LEN * 64) / 256, 256, 0, stream>>>(rtab);
  // 1. Wqkv [4096][6144] f32 -> WT [6144][4096] bf16
  transpose_convert<<<dim3(NFUSED / 64, MDIM / 64), 256, 0, stream>>>(
      Wqkv, WT, MDIM, NFUSED);
  // 2. QKV GEMM with fused bias + RoPE + head split (V transposed)
  gemm1_kernel<<<dim3(NFUSED / 256, S_LEN / 256), 512, 0, stream>>>(
      xb, WT, bqkv, rtab, Qb, Kb, Vt);
  // 3. Wo [4096][4096] f32 -> WoT [4096][4096] bf16 (reuses WT region)
  transpose_convert<<<dim3(MDIM / 64, MDIM / 64), 256, 0, stream>>>(Wo, WoT,
                                                                    MDIM, MDIM);
  // 4. causal GQA flash attention -> attnb bf16 (1D LPT grid)
  flash_kernel<<<S_LEN / 64 * NHEADS, 256, 0, stream>>>(Qb, Kb, Vt, attnb);
  // 5. output projection (overwrites xb scratch region of d_out)
  gemm2_kernel<<<dim3(MDIM / 256, S_LEN / 128), 512, 0, stream>>>(attnb, WoT,
                                                                  bo, out);
}

// Round 8
// 475.335 us; speedup vs baseline: 1.5943x; 1.0192x over previous
//
#include <hip/hip_runtime.h>
#include <hip/hip_bf16.h>
#include <math.h>

#define S_LEN  2048
#define MDIM   4096
#define NHEADS 32
#define NKV    8
#define HD     128
#define KVDIM  1024
#define NFUSED (MDIM + 2 * KVDIM) /* 6144 */

typedef short bf16x8 __attribute__((ext_vector_type(8)));
typedef float f32x4 __attribute__((ext_vector_type(4)));
typedef float f32x16 __attribute__((ext_vector_type(16)));

__device__ __forceinline__ unsigned short f2b(float f) {
  union { float f; unsigned int u; } v; v.f = f;
  unsigned int r = v.u + 0x7FFFu + ((v.u >> 16) & 1u);
  return (unsigned short)(r >> 16);
}
__device__ __forceinline__ float b2f(unsigned short h) {
  union { unsigned int u; float f; } v; v.u = ((unsigned int)h) << 16;
  return v.f;
}

// async global->LDS, 16B per lane; lds dest = wave-uniform base + lane*16
__device__ __forceinline__ void async_copy16(const void* g, void* l) {
  __builtin_amdgcn_global_load_lds(
      (const __attribute__((address_space(1))) unsigned int*)g,
      (__attribute__((address_space(3))) unsigned int*)l, 16, 0, 0);
}

// ---------------------------------------------------------------------------
// x f32 -> bf16 (one thread per 8 elements)
// ---------------------------------------------------------------------------
__global__ __launch_bounds__(256) void convert_x(
    const float* __restrict__ src, unsigned short* __restrict__ dst) {
  size_t i = (size_t)blockIdx.x * 256 + threadIdx.x;
  const float4 a = ((const float4*)src)[2 * i];
  const float4 b = ((const float4*)src)[2 * i + 1];
  unsigned short o[8] = {f2b(a.x), f2b(a.y), f2b(a.z), f2b(a.w),
                         f2b(b.x), f2b(b.y), f2b(b.z), f2b(b.w)};
  *(int4*)(dst + 8 * i) = *(const int4*)o;
}

// ---------------------------------------------------------------------------
// RoPE table: rtab[s*64+d] = (cos, sin)(s * 50000^(-d/64)). One-time, ~4us.
// ---------------------------------------------------------------------------
__global__ __launch_bounds__(256) void rope_table(float2* __restrict__ rtab) {
  int t = blockIdx.x * 256 + threadIdx.x;  // 0..131071
  int s = t >> 6, d = t & 63;
  float inv_freq = __expf(-0.16905903569f * (float)d);  // 50000^(-d/64)
  float ang = (float)s * inv_freq;
  rtab[t] = make_float2(cosf(ang), sinf(ang));
}

// ---------------------------------------------------------------------------
// Transpose + convert: W [K][N] f32 -> WT [N][K] bf16. 64x64 tiles.
// ---------------------------------------------------------------------------
__global__ __launch_bounds__(256) void transpose_convert(
    const float* __restrict__ W, unsigned short* __restrict__ WT, int K,
    int N) {
  __shared__ unsigned short t[64 * 72];  // [n][k], pad 64->72
  const int k0 = blockIdx.y << 6, n0 = blockIdx.x << 6;
  const int tid = threadIdx.x;
#pragma unroll
  for (int it = 0; it < 4; ++it) {
    int idx = it * 256 + tid;          // 0..1023
    int r = idx & 63;                  // k row
    int c = ((idx >> 6) & 15) << 2;    // n col group
    const float4 v = *(const float4*)(W + (size_t)(k0 + r) * N + n0 + c);
    t[(c + 0) * 72 + r] = f2b(v.x);
    t[(c + 1) * 72 + r] = f2b(v.y);
    t[(c + 2) * 72 + r] = f2b(v.z);
    t[(c + 3) * 72 + r] = f2b(v.w);
  }
  __syncthreads();
  const int n = tid >> 2, kk = (tid & 3) << 4;
  *(int4*)(WT + (size_t)(n0 + n) * K + k0 + kk) = *(int4*)&t[n * 72 + kk];
  *(int4*)(WT + (size_t)(n0 + n) * K + k0 + kk + 8) =
      *(int4*)&t[n * 72 + kk + 8];
}

// ---------------------------------------------------------------------------
// GEMM1: fused = xb[2048][4096](bf16) * WT^T + bqkv, RoPE + head-split
// epilogue. 256x256 tile, BK=64, 8 waves (2M x 4N), dbuf 128KiB LDS,
// 32x32x16 MFMA, single vmcnt(0)+barrier per K-tile.
//
// SWIZZLE FIX (round 6 regression): with hash=row&7 the 32x32 fragment
// read put the 4 lanes {x,x+8,x+16,x+24} (same l31&7, same lh) on the SAME
// swizzled chunk in rows 8 apart -> rows are 128B = bank-wrap -> 4-way
// conflict (SQ_LDS_BANK_CONFLICT 229K->9.67M, 124->140us). Generalized
// hash = (row ^ (row>>3)) & 7 maps those 4 lanes to 4 distinct chunks ->
// uniform 8 lanes/bank-group (LDS floor). Write side: dest row =
// c*64+wave*8+lr8 -> hash = lr8^wave (c*64 adds 8 to row>>3, =0 mod 8), so
// pre-swizzled source chunk = lc8^lr8^wave, constant across c. Read side:
// row = woff + l31 + i*32 (woff=0 mod 64) -> hash = base ^ (i&1 ? 4 : 0),
// base = (l31&7)^(l31>>3); even/odd i (jj) use chunk co / co^32.
// C/D: col=lane&31, row=(reg&3)+8*(reg>>2)+4*(lane>>5) [m74/m101].
// acc = f32x16[4][2], statically indexed (rule #20).
// ---------------------------------------------------------------------------
__global__ __launch_bounds__(512, 2) void gemm1_kernel(
    const unsigned short* __restrict__ xb,
    const unsigned short* __restrict__ WT, const float* __restrict__ bias,
    const float2* __restrict__ rtab, unsigned short* __restrict__ Qb,
    unsigned short* __restrict__ Kb, unsigned short* __restrict__ Vt) {
  // [slot][ A 256x64 | B 256x64 ] bf16 = 2 x 64KiB = 128KiB
  __shared__ unsigned short sm[2][32768];

  const int tid = threadIdx.x;
  const int bn = blockIdx.x, bm = blockIdx.y;
  const int lane = tid & 63, wave = tid >> 6;
  const int l31 = lane & 31, lh = lane >> 5;
  const int wrow = wave >> 2, wcol = wave & 3;  // 2M x 4N wave grid

  f32x16 acc[4][2];
#pragma unroll
  for (int i = 0; i < 4; ++i)
#pragma unroll
    for (int j = 0; j < 2; ++j)
#pragma unroll
      for (int r = 0; r < 16; ++r) acc[i][j][r] = 0.f;

  // staging: each copy = 64 rows over 8 waves (8 rows/wave); lane ->
  // (row lr8, phys chunk lc8). hash(destrow)=lr8^wave -> src chunk below.
  const int lr8 = lane >> 3, lc8 = lane & 7;
  const int baser = wave * 8 + lr8;                    // tile row (+c*64)
  const size_t swz = (size_t)((lc8 ^ lr8 ^ wave) << 3);  // pre-swizzle
  const unsigned short* sA = xb + (size_t)(bm * 256 + baser) * MDIM + swz;
  const unsigned short* sB = WT + (size_t)(bn * 256 + baser) * MDIM + swz;

  auto stage = [&](int slot, int k0) {
#pragma unroll
    for (int c = 0; c < 4; ++c) {
      unsigned short* dA = &sm[slot][(c * 64 + wave * 8) * 64];
      unsigned short* dB = &sm[slot][16384 + (c * 64 + wave * 8) * 64];
      async_copy16(sA + (size_t)c * 64 * MDIM + k0, dA);
      async_copy16(sB + (size_t)c * 64 * MDIM + k0, dB);
    }
  };

  // fragment-read invariants
  const int arow0 = wrow * 128 + l31;  // + i*32
  const int brow0 = wcol * 64 + l31;   // + jj*32
  const int base = (l31 & 7) ^ (l31 >> 3);

  stage(0, 0);  // prologue: K-tile 0 -> slot 0

  for (int kt = 0; kt < 64; ++kt) {
    const int p = kt & 1;
    // own 8 copies of tile kt are the only outstanding VMEM ops; each wave
    // drains ITS copies before the barrier => after barrier all landed.
    asm volatile("s_waitcnt vmcnt(0)" ::: "memory");
    __builtin_amdgcn_s_barrier();  // also: all waves done reading slot p^1
    __builtin_amdgcn_sched_barrier(0);

    if (kt < 63) stage(p ^ 1, (kt + 1) << 6);  // flies under this compute

    const unsigned short* Asl = &sm[p][0];
    const unsigned short* Bsl = &sm[p][16384];
    __builtin_amdgcn_s_setprio(1);
#pragma unroll
    for (int t = 0; t < 4; ++t) {  // k-step of 16
      const int coE = (((2 * t + lh) ^ base) << 3);  // even i/jj rows
      const int coO = coE ^ 32;                      // odd  i/jj rows (+4 hash)
      bf16x8 bfr[2], af[4];
      bfr[0] = *(const bf16x8*)&Bsl[(brow0) * 64 + coE];
      bfr[1] = *(const bf16x8*)&Bsl[(brow0 + 32) * 64 + coO];
      af[0] = *(const bf16x8*)&Asl[(arow0) * 64 + coE];
      af[1] = *(const bf16x8*)&Asl[(arow0 + 32) * 64 + coO];
      af[2] = *(const bf16x8*)&Asl[(arow0 + 64) * 64 + coE];
      af[3] = *(const bf16x8*)&Asl[(arow0 + 96) * 64 + coO];
#pragma unroll
      for (int i = 0; i < 4; ++i)
#pragma unroll
        for (int jj = 0; jj < 2; ++jj)
          acc[i][jj] = __builtin_amdgcn_mfma_f32_32x32x16_bf16(
              af[i], bfr[jj], acc[i][jj], 0, 0, 0);
    }
    __builtin_amdgcn_s_setprio(0);
  }
  __syncthreads();  // K-loop reads done before Ct overwrites staging LDS

  // ---- epilogue: two 128-col halves; Ct[256][132] reuses staging LDS ----
  unsigned short* Ct = &sm[0][0];
#pragma unroll 1
  for (int h = 0; h < 2; ++h) {
    const int slot = 2 * bn + h;  // 0..31 Q, 32..39 K, 40..47 V
    if ((wcol >> 1) == h) {       // waves owning this col half write acc
#pragma unroll
      for (int i = 0; i < 4; ++i)
#pragma unroll
        for (int jj = 0; jj < 2; ++jj) {
          int lc = (wcol & 1) * 64 + jj * 32 + l31;
          float bv = bias[slot * 128 + lc];
#pragma unroll
          for (int r = 0; r < 16; ++r) {
            int lrw = wrow * 128 + i * 32 + (r & 3) + 8 * (r >> 2) + 4 * lh;
            Ct[lrw * 132 + lc] = f2b(acc[i][jj][r] + bv);
          }
        }
    }
    __syncthreads();

    if (slot < 40) {
#pragma unroll 4
      for (int it = 0; it < 32; ++it) {
        int row = it * 8 + wave;  // 0..255
        int d = lane;
        float x1 = b2f(Ct[row * 132 + d]);
        float x2 = b2f(Ct[row * 132 + d + 64]);
        int s = bm * 256 + row;
        float2 cs = rtab[s * 64 + d];  // (cos, sin) precomputed
        float o1 = x1 * cs.x - x2 * cs.y;
        float o2 = x2 * cs.x + x1 * cs.y;
        unsigned short* dst;
        if (slot < 32)
          dst = Qb + ((size_t)slot * S_LEN + s) * HD;
        else
          dst = Kb + ((size_t)(slot - 32) * S_LEN + s) * HD;
        dst[d] = f2b(o1);
        dst[d + 64] = f2b(o2);
      }
    } else {
      // V: write transposed Vt[g][d][s], coalesced along s
      const int g = slot - 40;
      unsigned short* Vtg = Vt + (size_t)g * HD * S_LEN;  // [128][2048]
      const int dp = tid >> 3;         // d-pair 0..63
      const int sq = (tid & 7) << 5;   // s-eighth 0,32,..,224
      unsigned short buf0[32], buf1[32];
#pragma unroll
      for (int i = 0; i < 32; ++i) {
        unsigned int w = *(const unsigned int*)&Ct[(sq + i) * 132 + 2 * dp];
        buf0[i] = (unsigned short)(w & 0xffffu);
        buf1[i] = (unsigned short)(w >> 16);
      }
      const int s0 = bm * 256 + sq;
#pragma unroll
      for (int c = 0; c < 2; ++c) {
        unsigned short* dst = Vtg + (size_t)(2 * dp + c) * S_LEN + s0;
        const unsigned short* b = c ? buf1 : buf0;
#pragma unroll
        for (int q4 = 0; q4 < 4; ++q4)
          *(int4*)(dst + q4 * 8) = *(const int4*)(b + q4 * 8);
      }
    }
    __syncthreads();  // pass-h reads done before pass h+1 overwrites Ct
  }
}

// ---------------------------------------------------------------------------
// GEMM2: out = attnb[2048][4096](bf16) * WoT^T + bo (f32 out).
// BM=128 x BN=256 (grid 16x16 = 256 blocks = 1/CU), BK=64, 8 waves (2M x 4N,
// 64x64 per wave), dbuf 96KiB LDS, 32x32x16 MFMA, single barrier per K-tile.
// Same generalized hash swizzle as gemm1.
// ---------------------------------------------------------------------------
__global__ __launch_bounds__(512, 2) void gemm2_kernel(
    const unsigned short* __restrict__ Ab16,
    const unsigned short* __restrict__ BT, const float* __restrict__ bias,
    float* __restrict__ C) {
  // [slot][ A 128x64 | B 256x64 ] bf16 = 2 x 48KiB = 96KiB
  __shared__ unsigned short sm[2][24576];

  const int tid = threadIdx.x;
  const int bn = blockIdx.x, bm = blockIdx.y;  // bn: N/256, bm: M/128
  const int lane = tid & 63, wave = tid >> 6;
  const int l31 = lane & 31, lh = lane >> 5;
  const int wrow = wave >> 2, wcol = wave & 3;  // 2M x 4N wave grid

  f32x16 acc[2][2];
#pragma unroll
  for (int i = 0; i < 2; ++i)
#pragma unroll
    for (int j = 0; j < 2; ++j)
#pragma unroll
      for (int r = 0; r < 16; ++r) acc[i][j][r] = 0.f;

  const int lr8 = lane >> 3, lc8 = lane & 7;
  const int baser = wave * 8 + lr8;
  const size_t swz = (size_t)((lc8 ^ lr8 ^ wave) << 3);
  const unsigned short* sA = Ab16 + (size_t)(bm * 128 + baser) * MDIM + swz;
  const unsigned short* sB = BT + (size_t)(bn * 256 + baser) * MDIM + swz;

  auto stage = [&](int slot, int k0) {
#pragma unroll
    for (int c = 0; c < 2; ++c)
      async_copy16(sA + (size_t)c * 64 * MDIM + k0,
                   &sm[slot][(c * 64 + wave * 8) * 64]);
#pragma unroll
    for (int c = 0; c < 4; ++c)
      async_copy16(sB + (size_t)c * 64 * MDIM + k0,
                   &sm[slot][8192 + (c * 64 + wave * 8) * 64]);
  };

  const int arow0 = wrow * 64 + l31;  // + i*32
  const int brow0 = wcol * 64 + l31;  // + jj*32
  const int base = (l31 & 7) ^ (l31 >> 3);

  stage(0, 0);  // prologue: K-tile 0 -> slot 0

#pragma unroll 1
  for (int kt = 0; kt < 64; ++kt) {
    const int p = kt & 1;
    asm volatile("s_waitcnt vmcnt(0)" ::: "memory");
    __builtin_amdgcn_s_barrier();
    __builtin_amdgcn_sched_barrier(0);

    if (kt < 63) stage(p ^ 1, (kt + 1) << 6);

    const unsigned short* Asl = &sm[p][0];
    const unsigned short* Bsl = &sm[p][8192];
    __builtin_amdgcn_s_setprio(1);
#pragma unroll
    for (int t = 0; t < 4; ++t) {
      const int coE = (((2 * t + lh) ^ base) << 3);
      const int coO = coE ^ 32;
      bf16x8 bfr[2], af[2];
      bfr[0] = *(const bf16x8*)&Bsl[(brow0) * 64 + coE];
      bfr[1] = *(const bf16x8*)&Bsl[(brow0 + 32) * 64 + coO];
      af[0] = *(const bf16x8*)&Asl[(arow0) * 64 + coE];
      af[1] = *(const bf16x8*)&Asl[(arow0 + 32) * 64 + coO];
#pragma unroll
      for (int i = 0; i < 2; ++i)
#pragma unroll
        for (int jj = 0; jj < 2; ++jj)
          acc[i][jj] = __builtin_amdgcn_mfma_f32_32x32x16_bf16(
              af[i], bfr[jj], acc[i][jj], 0, 0, 0);
    }
    __builtin_amdgcn_s_setprio(0);
  }

  // epilogue: direct f32 store with bias
#pragma unroll
  for (int i = 0; i < 2; ++i)
#pragma unroll
    for (int jj = 0; jj < 2; ++jj) {
      int gcol = bn * 256 + wcol * 64 + jj * 32 + l31;
      float bv = bias[gcol];
#pragma unroll
      for (int r = 0; r < 16; ++r) {
        int grow =
            bm * 128 + wrow * 64 + i * 32 + (r & 3) + 8 * (r >> 2) + 4 * lh;
        C[(size_t)grow * MDIM + gcol] = acc[i][jj][r] + bv;
      }
    }
}

// ---------------------------------------------------------------------------
// Flash attention, causal, GQA. Fixed-max softmax (scores bounded; exp(s-12)
// cannot overflow, o/l unchanged). Q in registers. K/V double-buffered LDS
// via global_load_lds with XOR-swizzled layout (pre-swizzled global source,
// linear LDS dest). One vmcnt(0)+barrier per KV-tile; prefetch issued after
// the barrier flies under the whole compute phase. Ps fence: lgkmcnt only.
// Row-sums via ones-MFMA. 1D LPT grid.
// ---------------------------------------------------------------------------
__device__ __forceinline__ void stage_kv(const unsigned short* __restrict__ Kg,
                                         const unsigned short* __restrict__ Vg,
                                         int jtile, unsigned short* KsBuf,
                                         unsigned short* VsBuf, int wv,
                                         int lane) {
  const unsigned short* kg = Kg + (size_t)jtile * 64 * HD;
  const unsigned short* vg = Vg + jtile * 64;
#pragma unroll
  for (int it = 0; it < 4; ++it) {
    // K: 4 rows x 256B per copy; lane -> row base+(l>>4), chunk l&15
    int kr = wv * 16 + it * 4 + (lane >> 4);
    async_copy16(kg + (size_t)kr * HD + (((lane & 15) ^ (kr & 7)) << 3),
                 KsBuf + (wv * 16 + it * 4) * 128);
    // V: 8 rows x 128B per copy; lane -> row base+(l>>3), chunk l&7
    int vr = wv * 32 + it * 8 + (lane >> 3);
    async_copy16(vg + (size_t)vr * S_LEN + (((lane & 7) ^ (vr & 7)) << 3),
                 VsBuf + (wv * 32 + it * 8) * 64);
  }
}

__global__ __launch_bounds__(256, 2) void flash_kernel(
    const unsigned short* __restrict__ Qb, const unsigned short* __restrict__ Kb,
    const unsigned short* __restrict__ Vt, unsigned short* __restrict__ attnb) {
  __shared__ __align__(16) unsigned short Ks[2][64 * 128];  // [krow][d] swz
  __shared__ __align__(16) unsigned short Vs[2][128 * 64];  // [d][kvpos] swz
  __shared__ __align__(16) unsigned short Ps[64 * 72];      // [qrow][kvpos]

  const int tid = threadIdx.x;
  const int bid = blockIdx.x;
  const int h = bid & 31;
  const int qt = 31 - (bid >> 5);  // heavy tiles dispatch first (LPT)
  const int g = h >> 2;
  const int wv = tid >> 6, lane = tid & 63;
  const int lrow = lane & 15, quad = lane >> 4;
  const float scale = 0.08838834764831845f;  // 1/sqrt(128)

  const unsigned short* Qg = Qb + ((size_t)h * S_LEN + qt * 64) * HD;
  bf16x8 qf[4];
#pragma unroll
  for (int ks = 0; ks < 4; ++ks)
    qf[ks] = *(const bf16x8*)(Qg + (size_t)(wv * 16 + lrow) * HD + ks * 32 +
                              quad * 8);

  // all-ones bf16 B-fragment for row-sum MFMA
  bf16x8 ones;
#pragma unroll
  for (int i = 0; i < 8; ++i) ones[i] = (short)0x3F80;

  const unsigned short* Kg = Kb + (size_t)g * S_LEN * HD;   // [s][d]
  const unsigned short* Vg = Vt + (size_t)g * HD * S_LEN;   // [d][s]

  f32x4 l_acc = {0.f, 0.f, 0.f, 0.f};
  f32x4 o_acc[8];
#pragma unroll
  for (int jc = 0; jc < 8; ++jc) {
    f32x4 z = {0.f, 0.f, 0.f, 0.f};
    o_acc[jc] = z;
  }

  // prologue: stage tile 0 into buffer 0
  stage_kv(Kg, Vg, 0, &Ks[0][0], &Vs[0][0], wv, lane);

  for (int jt = 0; jt <= qt; ++jt) {
    const int cb = jt & 1;
    // own copies of tile jt are the only outstanding VMEM ops
    asm volatile("s_waitcnt vmcnt(0)" ::: "memory");
    __builtin_amdgcn_s_barrier();  // all waves' copies landed; all waves
                                   // done reading buf cb from iter jt-2
    __builtin_amdgcn_sched_barrier(0);

    if (jt < qt)  // prefetch next tile; flies under this iter's compute
      stage_kv(Kg, Vg, jt + 1, &Ks[cb ^ 1][0], &Vs[cb ^ 1][0], wv, lane);

    // S = Q K^T (wave's 16 rows x 64 cols)
    f32x4 s_acc[4];
#pragma unroll
    for (int j = 0; j < 4; ++j) {
      f32x4 z = {0.f, 0.f, 0.f, 0.f};
      s_acc[j] = z;
    }
#pragma unroll
    for (int ks = 0; ks < 4; ++ks)
#pragma unroll
      for (int j = 0; j < 4; ++j) {
        int row = j * 16 + lrow;
        bf16x8 bk = *(const bf16x8*)&Ks[cb][row * 128 +
                                           (((ks * 4 + quad) ^ (row & 7)) << 3)];
        s_acc[j] = __builtin_amdgcn_mfma_f32_16x16x32_bf16(qf[ks], bk,
                                                           s_acc[j], 0, 0, 0);
      }

    // fixed-max softmax: p = exp(s*scale - 12); mask only on diagonal tile
    if (jt == qt) {
#pragma unroll
      for (int r = 0; r < 4; ++r) {
        int grow = qt * 64 + wv * 16 + quad * 4 + r;
#pragma unroll
        for (int j = 0; j < 4; ++j) {
          int gcol = jt * 64 + j * 16 + lrow;
          float p =
              (gcol <= grow) ? __expf(s_acc[j][r] * scale - 12.0f) : 0.f;
          Ps[(wv * 16 + quad * 4 + r) * 72 + j * 16 + lrow] = f2b(p);
        }
      }
    } else {
#pragma unroll
      for (int r = 0; r < 4; ++r)
#pragma unroll
        for (int j = 0; j < 4; ++j) {
          float p = __expf(s_acc[j][r] * scale - 12.0f);
          Ps[(wv * 16 + quad * 4 + r) * 72 + j * 16 + lrow] = f2b(p);
        }
    }
    // Ps band is wave-private: LDS drain only (must NOT drain vmcnt — the
    // next tile's global_load_lds copies are in flight)
    asm volatile("s_waitcnt lgkmcnt(0)" ::: "memory");
    __builtin_amdgcn_sched_barrier(0);

    // O += P V (16 rows x 128 cols, K=64); l += P * ones
#pragma unroll
    for (int kk = 0; kk < 2; ++kk) {
      bf16x8 ap =
          *(const bf16x8*)&Ps[(wv * 16 + lrow) * 72 + kk * 32 + 8 * quad];
      l_acc = __builtin_amdgcn_mfma_f32_16x16x32_bf16(ap, ones, l_acc, 0, 0, 0);
#pragma unroll
      for (int jc = 0; jc < 8; ++jc) {
        int row = jc * 16 + lrow;
        bf16x8 bv = *(const bf16x8*)&Vs[cb][row * 64 +
                                            (((kk * 4 + quad) ^ (row & 7)) << 3)];
        o_acc[jc] = __builtin_amdgcn_mfma_f32_16x16x32_bf16(ap, bv, o_acc[jc],
                                                            0, 0, 0);
      }
    }
    __builtin_amdgcn_s_barrier();  // all waves done reading buf cb before
                                   // iter jt+1 issues copies into buf cb
  }

  // epilogue: O / l -> attnb[s][h*128+d] (bf16)
#pragma unroll
  for (int r = 0; r < 4; ++r) {
    float inv_l = 1.0f / l_acc[r];
    int row = qt * 64 + wv * 16 + quad * 4 + r;
#pragma unroll
    for (int jc = 0; jc < 8; ++jc) {
      int col = jc * 16 + lrow;
      attnb[(size_t)row * MDIM + h * HD + col] = f2b(o_acc[jc][r] * inv_l);
    }
  }
}

// ---------------------------------------------------------------------------
extern "C" void kernel_launch(void* const* d_in, const int* in_sizes, int n_in,
                              void* d_out, int out_size, void* d_ws,
                              size_t ws_size, hipStream_t stream) {
  const float* x = (const float*)d_in[0];
  const float* Wqkv = (const float*)d_in[1];
  const float* bqkv = (const float*)d_in[2];
  const float* Wo = (const float*)d_in[3];
  const float* bo = (const float*)d_in[4];
  float* out = (float*)d_out;

  unsigned char* ws = (unsigned char*)d_ws;
  // region A [0, 50331648): phase1 = WT (6144x4096 bf16);
  //                         phase2 = WoT (33554432) + attnb (16777216)
  unsigned short* WT = (unsigned short*)ws;
  unsigned short* WoT = (unsigned short*)ws;
  unsigned short* attnb = (unsigned short*)(ws + 33554432);
  // region B: Q/K head-major bf16, V transposed [g][d][s]
  unsigned short* Qb = (unsigned short*)(ws + 50331648);  // 32*2048*128
  unsigned short* Kb = (unsigned short*)(ws + 67108864);  // 8*2048*128
  unsigned short* Vt = (unsigned short*)(ws + 71303168);  // 8*128*2048
  // d_out scratch: xb (bf16 x) in [0,16MB); RoPE table in [16MB,17MB).
  // Both consumed before gemm2 overwrites d_out with the final output.
  unsigned short* xb = (unsigned short*)d_out;
  float2* rtab = (float2*)((unsigned char*)d_out + 16777216);

  // 0. x f32 -> bf16 (into d_out scratch) + RoPE cos/sin table
  convert_x<<<(S_LEN * MDIM / 8) / 256, 256, 0, stream>>>(x, xb);
  rope_table<<<(S_LEN * 64) / 256, 256, 0, stream>>>(rtab);
  // 1. Wqkv [4096][6144] f32 -> WT [6144][4096] bf16
  transpose_convert<<<dim3(NFUSED / 64, MDIM / 64), 256, 0, stream>>>(
      Wqkv, WT, MDIM, NFUSED);
  // 2. QKV GEMM with fused bias + RoPE + head split (V transposed)
  gemm1_kernel<<<dim3(NFUSED / 256, S_LEN / 256), 512, 0, stream>>>(
      xb, WT, bqkv, rtab, Qb, Kb, Vt);
  // 3. Wo [4096][4096] f32 -> WoT [4096][4096] bf16 (reuses WT region)
  transpose_convert<<<dim3(MDIM / 64, MDIM / 64), 256, 0, stream>>>(Wo, WoT,
                                                                    MDIM, MDIM);
  // 4. causal GQA flash attention -> attnb bf16 (1D LPT grid)
  flash_kernel<<<S_LEN / 64 * NHEADS, 256, 0, stream>>>(Qb, Kb, Vt, attnb);
  // 5. output projection (overwrites xb scratch region of d_out)
  gemm2_kernel<<<dim3(MDIM / 256, S_LEN / 128), 512, 0, stream>>>(attnb, WoT,
                                                                  bo, out);
}